// Round 7
// baseline (252.548 us; speedup 1.0000x reference)
//
#include <hip/hip_runtime.h>
#include <hip/hip_bf16.h>

// MHA: x[2,2048,1024]; q = x@w_k^T (faithful swap), k = x@w_q^T, v = x@w_v^T
// scores = QK^T * (1/sqrt(1024)), causal mask, softmax, ctx = P@V
// out = ctx@w_o^T + b_o   (fp32 out)

typedef __attribute__((ext_vector_type(8))) short bf16x8;
typedef __attribute__((ext_vector_type(4))) float f32x4;

#define SEQ 2048
#define NHEAD 16
#define HD 64
#define M_TOT 4096   // B*L

static __device__ __forceinline__ unsigned short f2bf(float f) {
  unsigned int u = __float_as_uint(f);
  u += 0x7fff + ((u >> 16) & 1);          // RNE
  return (unsigned short)(u >> 16);
}
static __device__ __forceinline__ float bf2f(unsigned short u) {
  return __uint_as_float(((unsigned int)u) << 16);
}

static __device__ __forceinline__ void gload16(const unsigned short* g, unsigned short* l) {
  __builtin_amdgcn_global_load_lds(
      (const __attribute__((address_space(1))) unsigned int*)g,
      (__attribute__((address_space(3))) unsigned int*)l, 16, 0, 0);
}

// ---------------- fp32 -> bf16 convert, 4 elems/thread ----------------
__global__ void cvt_kernel(const float* __restrict__ in, unsigned short* __restrict__ out, int n) {
  int i = (blockIdx.x * blockDim.x + threadIdx.x) * 4;
  if (i >= n) return;
  float4 v = *reinterpret_cast<const float4*>(in + i);
  ushort4 o;
  o.x = f2bf(v.x); o.y = f2bf(v.y); o.z = f2bf(v.z); o.w = f2bf(v.w);
  *reinterpret_cast<ushort4*>(out + i) = o;
}

// ---------------- NT GEMM: C[M,N] = A[M,K] * B[N,K]^T ----------------
// 128x128 tile, 4 waves (2x2), BK=64, m97-style 2-barrier loop.
// mode 0: scatter to qb/kb ([b][h][l][d]) and vtb ([b][h][d][l]), bf16
// mode 1: out[m*1024+n] = acc + bias[n], fp32
__global__ __launch_bounds__(256) void gemm_nt(
    const unsigned short* __restrict__ A,
    const unsigned short* __restrict__ B,
    int K, int mode,
    unsigned short* __restrict__ qb,
    unsigned short* __restrict__ kb,
    unsigned short* __restrict__ vtb,
    const float* __restrict__ bias,
    float* __restrict__ outf)
{
  __shared__ unsigned short lds_a[128 * 64];
  __shared__ unsigned short lds_b[128 * 64];
  const int t = threadIdx.x;
  const int wid = t >> 6;
  const int lane = t & 63;
  const int lr = lane & 15;
  const int lg = lane >> 4;
  const int tm = blockIdx.x * 128;
  const int tn = blockIdx.y * 128;
  const int wr = (wid >> 1) * 64;
  const int wc = (wid & 1) * 64;

  const unsigned short* Ab = A + (size_t)tm * K;
  const unsigned short* Bb = B + (size_t)tn * K;
  const int srow = wid * 8 + (lane >> 3);   // row within a 32-row chunk
  const int scol = (lane & 7) * 8;          // bf16 col (16B granules)

  f32x4 acc[4][4];
  #pragma unroll
  for (int i = 0; i < 4; ++i)
    #pragma unroll
    for (int j = 0; j < 4; ++j) acc[i][j] = (f32x4){0.f, 0.f, 0.f, 0.f};

  for (int k0 = 0; k0 < K; k0 += 64) {
    #pragma unroll
    for (int i = 0; i < 4; ++i) {
      gload16(Ab + (size_t)(i * 32 + srow) * K + k0 + scol, &lds_a[(i * 32 + wid * 8) * 64]);
      gload16(Bb + (size_t)(i * 32 + srow) * K + k0 + scol, &lds_b[(i * 32 + wid * 8) * 64]);
    }
    __syncthreads();
    #pragma unroll
    for (int kk = 0; kk < 2; ++kk) {
      bf16x8 af[4], bfr[4];
      #pragma unroll
      for (int mi = 0; mi < 4; ++mi)
        af[mi] = *reinterpret_cast<const bf16x8*>(&lds_a[(wr + mi * 16 + lr) * 64 + kk * 32 + lg * 8]);
      #pragma unroll
      for (int ni = 0; ni < 4; ++ni)
        bfr[ni] = *reinterpret_cast<const bf16x8*>(&lds_b[(wc + ni * 16 + lr) * 64 + kk * 32 + lg * 8]);
      #pragma unroll
      for (int mi = 0; mi < 4; ++mi)
        #pragma unroll
        for (int ni = 0; ni < 4; ++ni)
          acc[mi][ni] = __builtin_amdgcn_mfma_f32_16x16x32_bf16(af[mi], bfr[ni], acc[mi][ni], 0, 0, 0);
    }
    __syncthreads();
  }

  if (mode == 0) {
    #pragma unroll
    for (int mi = 0; mi < 4; ++mi)
      #pragma unroll
      for (int ni = 0; ni < 4; ++ni)
        #pragma unroll
        for (int r = 0; r < 4; ++r) {
          int gm = tm + wr + mi * 16 + lg * 4 + r;
          int gn = tn + wc + ni * 16 + lr;
          float v = acc[mi][ni][r];
          unsigned short bv = f2bf(v);
          int bb = gm >> 11, l = gm & 2047;
          int tsel = gn >> 10, o = gn & 1023;
          int h = o >> 6, d = o & 63;
          if (tsel == 0)      qb[(((size_t)(bb * NHEAD + h)) * SEQ + l) * HD + d] = bv;
          else if (tsel == 1) kb[(((size_t)(bb * NHEAD + h)) * SEQ + l) * HD + d] = bv;
          else                vtb[(((size_t)(bb * NHEAD + h)) * HD + d) * SEQ + l] = bv;
        }
  } else {
    #pragma unroll
    for (int mi = 0; mi < 4; ++mi)
      #pragma unroll
      for (int ni = 0; ni < 4; ++ni)
        #pragma unroll
        for (int r = 0; r < 4; ++r) {
          int gm = tm + wr + mi * 16 + lg * 4 + r;
          int gn = tn + wc + ni * 16 + lr;
          outf[(size_t)gm * 1024 + gn] = acc[mi][ni][r] + bias[gn];
        }
  }
}

// ---------------- flash attention, causal, KV-parity split ----------------
// Grid 512 blocks x 512 threads (8 waves). xcd = id&7 owns 4 (b,h) pairs;
// block processes q-tiles (31-pair, pair) sequentially (perfect balance:
// 17 steps per block). Within a q-tile, wave-group g = wid>>2 handles KV
// tiles of parity g (own double-buffered LDS stream) -> per-wave work
// halves and 16 waves/CU (2 blocks x 8 waves) hide latency. Partial
// (m, l, O) merged per phase via LDS scratch overlaid on the K staging
// buffers. K tile [kv=64][d=64], V^T tile [d=64][kv=64], XOR-swizzled via
// pre-swizzled global source (LDS[r][gr] = G[r][gr ^ (r&7)], 16B granules).
// Defer-max (THR=8): skip the O/ls rescale unless running max grew by >8.
__global__ __launch_bounds__(512) void attn_kernel(
    const unsigned short* __restrict__ qb,
    const unsigned short* __restrict__ kb,
    const unsigned short* __restrict__ vtb,
    unsigned short* __restrict__ ctxb)
{
  __shared__ unsigned short kt_lds[2][2][64 * 64];   // [group][dbuf]
  __shared__ unsigned short vt_lds[2][2][64 * 64];
  __shared__ unsigned short p_lds[8][16 * 64];

  const int t = threadIdx.x;
  const int wid = t >> 6;        // 0..7
  const int g = wid >> 2;        // KV parity group
  const int w3 = wid & 3;        // wave within group; owns q-rows w3*16..
  const int lane = t & 63;
  const int lr = lane & 15;
  const int lg = lane >> 4;

  const int id = blockIdx.x;
  const int xcd = id & 7;
  const int chunk = id >> 3;              // 0..63
  const int bh = xcd * 4 + (chunk >> 4);  // 4 (b,h) pairs per XCD
  const int pair = chunk & 15;            // 0..15
  const int b = bh >> 4, h = bh & 15;

  const float csc = (1.0f / 32.0f) * 1.44269504f;  // 1/sqrt(1024) * log2(e)

  const unsigned short* Kp = kb + (size_t)bh * SEQ * HD;   // row kv, stride HD
  const unsigned short* Vp = vtb + (size_t)bh * HD * SEQ;  // row d,  stride SEQ
  const int sr_ = lane >> 3;   // 0..7: row within an 8-row wave chunk
  const int sg_ = lane & 7;    // 0..7: 16B granule

  auto stage = [&](int buf, int kv0) {   // group g's 4 waves stage one tile
    #pragma unroll
    for (int i = 0; i < 2; ++i) {
      int r = i * 32 + w3 * 8 + sr_;
      int gr = sg_ ^ (r & 7);   // pre-swizzled source granule
      gload16(Kp + (size_t)(kv0 + r) * HD + gr * 8, &kt_lds[g][buf][(i * 32 + w3 * 8) * 64]);
      gload16(Vp + (size_t)r * SEQ + kv0 + gr * 8, &vt_lds[g][buf][(i * 32 + w3 * 8) * 64]);
    }
  };

  for (int ph = 0; ph < 2; ++ph) {
    const int qtile = ph ? pair : (31 - pair);
    const int qw = qtile * 64 + w3 * 16;

    // Q fragments, scale folded in
    const unsigned short* Qp = qb + ((size_t)bh * SEQ + qw) * HD;
    bf16x8 aq[2];
    #pragma unroll
    for (int kk = 0; kk < 2; ++kk) {
      bf16x8 raw = *reinterpret_cast<const bf16x8*>(&Qp[lr * HD + kk * 32 + lg * 8]);
      #pragma unroll
      for (int j = 0; j < 8; ++j)
        aq[kk][j] = (short)f2bf(bf2f((unsigned short)raw[j]) * csc);
    }

    f32x4 oacc[4];
    #pragma unroll
    for (int ni = 0; ni < 4; ++ni) oacc[ni] = (f32x4){0.f, 0.f, 0.f, 0.f};
    float m_[4], ls[4];
    #pragma unroll
    for (int r = 0; r < 4; ++r) { m_[r] = -INFINITY; ls[r] = 0.f; }

    if (g <= qtile) stage(0, g * 64);   // group's first tile (parity g)
    __syncthreads();
    int cur = 0;

    const int nsteps = (qtile + 2) >> 1;   // ceil((qtile+1)/2)
    for (int s = 0; s < nsteps; ++s) {
      const int kt = 2 * s + g;
      const int kv0 = kt * 64;
      if (kt + 2 <= qtile) stage(cur ^ 1, kv0 + 128);   // prefetch own stream

      if (kt <= qtile) {
        // S = Q K^T (log2 domain; scale folded into Q)
        const char* kbase = (const char*)&kt_lds[g][cur][0];
        f32x4 s4[4];
        #pragma unroll
        for (int ni = 0; ni < 4; ++ni) {
          int row = ni * 16 + lr;
          int xr = (row & 7) << 4;
          bf16x8 b0 = *reinterpret_cast<const bf16x8*>(kbase + (row * 128 + ((lg * 16) ^ xr)));
          bf16x8 b1 = *reinterpret_cast<const bf16x8*>(kbase + (row * 128 + ((64 + lg * 16) ^ xr)));
          s4[ni] = (f32x4){0.f, 0.f, 0.f, 0.f};
          s4[ni] = __builtin_amdgcn_mfma_f32_16x16x32_bf16(aq[0], b0, s4[ni], 0, 0, 0);
          s4[ni] = __builtin_amdgcn_mfma_f32_16x16x32_bf16(aq[1], b1, s4[ni], 0, 0, 0);
        }

        if (kt == qtile) {   // causal mask, diagonal tile only
          #pragma unroll
          for (int ni = 0; ni < 4; ++ni)
            #pragma unroll
            for (int r = 0; r < 4; ++r) {
              int kv = kv0 + ni * 16 + lr;
              int qr = qw + lg * 4 + r;
              if (kv > qr) s4[ni][r] = -INFINITY;
            }
        }

        float rmax[4];
        #pragma unroll
        for (int r = 0; r < 4; ++r)
          rmax[r] = fmaxf(fmaxf(s4[0][r], s4[1][r]), fmaxf(s4[2][r], s4[3][r]));
        #pragma unroll
        for (int off = 1; off < 16; off <<= 1)
          #pragma unroll
          for (int r = 0; r < 4; ++r) rmax[r] = fmaxf(rmax[r], __shfl_xor(rmax[r], off));

        // defer-max: rescale only when max grew by > 8 (P bounded by 2^8)
        bool need = (rmax[0] > m_[0] + 8.f) | (rmax[1] > m_[1] + 8.f) |
                    (rmax[2] > m_[2] + 8.f) | (rmax[3] > m_[3] + 8.f);
        if (__any(need)) {
          #pragma unroll
          for (int r = 0; r < 4; ++r) {
            float mn = fmaxf(m_[r], rmax[r]);
            float f = exp2f(m_[r] - mn);
            m_[r] = mn;
            ls[r] *= f;
            #pragma unroll
            for (int ni = 0; ni < 4; ++ni) oacc[ni][r] *= f;
          }
        }

        float psum[4] = {0.f, 0.f, 0.f, 0.f};
        char* pbase = (char*)&p_lds[wid][0];
        #pragma unroll
        for (int ni = 0; ni < 4; ++ni)
          #pragma unroll
          for (int r = 0; r < 4; ++r) {
            float p = exp2f(s4[ni][r] - m_[r]);
            psum[r] += p;
            int row = lg * 4 + r;
            *reinterpret_cast<unsigned short*>(
                pbase + ((row * 128 + ni * 32 + lr * 2) ^ ((row & 7) << 4))) = f2bf(p);
          }
        #pragma unroll
        for (int off = 1; off < 16; off <<= 1)
          #pragma unroll
          for (int r = 0; r < 4; ++r) psum[r] += __shfl_xor(psum[r], off);
        #pragma unroll
        for (int r = 0; r < 4; ++r) ls[r] += psum[r];

        // P fragments (wave-private LDS; in-order DS within the wave)
        int xp = (lr & 7) << 4;
        bf16x8 pa0 = *reinterpret_cast<const bf16x8*>(pbase + (lr * 128 + ((lg * 16) ^ xp)));
        bf16x8 pa1 = *reinterpret_cast<const bf16x8*>(pbase + (lr * 128 + ((64 + lg * 16) ^ xp)));

        // ctx += P V : B rows are d (V^T tile), K-contig in kv
        const char* vbase = (const char*)&vt_lds[g][cur][0];
        #pragma unroll
        for (int ni = 0; ni < 4; ++ni) {
          int row = ni * 16 + lr;
          int xr = (row & 7) << 4;
          bf16x8 v0 = *reinterpret_cast<const bf16x8*>(vbase + (row * 128 + ((lg * 16) ^ xr)));
          bf16x8 v1 = *reinterpret_cast<const bf16x8*>(vbase + (row * 128 + ((64 + lg * 16) ^ xr)));
          oacc[ni] = __builtin_amdgcn_mfma_f32_16x16x32_bf16(pa0, v0, oacc[ni], 0, 0, 0);
          oacc[ni] = __builtin_amdgcn_mfma_f32_16x16x32_bf16(pa1, v1, oacc[ni], 0, 0, 0);
        }
      }

      __syncthreads();   // drains vmcnt: staged tiles complete; buffers free
      cur ^= 1;
    }

    // ---- merge group partials (scratch overlaid on K staging buffers) ----
    float* msc = (float*)&kt_lds[0][0][0];   // 4 waves x 64 lanes x 25 f32 = 25.6KB
    if (g == 1) {
      float* slot = msc + (size_t)(w3 * 64 + lane) * 25;
      #pragma unroll
      for (int ni = 0; ni < 4; ++ni)
        #pragma unroll
        for (int r = 0; r < 4; ++r) slot[ni * 4 + r] = oacc[ni][r];
      #pragma unroll
      for (int r = 0; r < 4; ++r) { slot[16 + r] = m_[r]; slot[20 + r] = ls[r]; }
    }
    __syncthreads();
    if (g == 0) {
      const float* slot = msc + (size_t)(w3 * 64 + lane) * 25;
      #pragma unroll
      for (int r = 0; r < 4; ++r) {
        float m1 = slot[16 + r], l1 = slot[20 + r];
        float ms = fmaxf(m_[r], m1);
        float f0 = exp2f(m_[r] - ms);
        float f1 = exp2f(m1 - ms);
        float li = ls[r] * f0 + l1 * f1;
        float inv = 1.0f / li;
        int qr = qw + lg * 4 + r;
        #pragma unroll
        for (int ni = 0; ni < 4; ++ni) {
          float o = oacc[ni][r] * f0 + slot[ni * 4 + r] * f1;
          int d = ni * 16 + lr;
          ctxb[((size_t)b * SEQ + qr) * 1024 + h * HD + d] = f2bf(o * inv);
        }
      }
    }
    __syncthreads();   // merge reads done before next phase overwrites staging
  }
}

extern "C" void kernel_launch(void* const* d_in, const int* in_sizes, int n_in,
                              void* d_out, int out_size, void* d_ws, size_t ws_size,
                              hipStream_t stream) {
  const float* x   = (const float*)d_in[0];
  const float* w_k = (const float*)d_in[1];
  const float* w_q = (const float*)d_in[2];
  const float* w_v = (const float*)d_in[3];
  const float* w_o = (const float*)d_in[4];
  const float* b_o = (const float*)d_in[5];
  float* out = (float*)d_out;

  char* ws = (char*)d_ws;
  unsigned short* xb   = (unsigned short*)(ws + 0);          //  8 MB [4096][1024]
  unsigned short* wqkv = (unsigned short*)(ws + 8388608);    //  6 MB [3072][1024]  (w_k;w_q;w_v)
  unsigned short* wob  = (unsigned short*)(ws + 14680064);   //  2 MB [1024][1024]
  unsigned short* qb   = (unsigned short*)(ws + 16777216);   //  8 MB [b][h][l][d]
  unsigned short* kb   = (unsigned short*)(ws + 25165824);   //  8 MB [b][h][l][d]
  unsigned short* vtb  = (unsigned short*)(ws + 33554432);   //  8 MB [b][h][d][l]
  unsigned short* ctxb = xb;                                  // reuse x region

  int n = M_TOT * 1024;
  cvt_kernel<<<n / 1024, 256, 0, stream>>>(x, xb, n);
  n = 1024 * 1024;
  cvt_kernel<<<n / 1024, 256, 0, stream>>>(w_k, wqkv, n);
  cvt_kernel<<<n / 1024, 256, 0, stream>>>(w_q, wqkv + 1048576, n);
  cvt_kernel<<<n / 1024, 256, 0, stream>>>(w_v, wqkv + 2097152, n);
  cvt_kernel<<<n / 1024, 256, 0, stream>>>(w_o, wob, n);

  // QKV: A = xb [4096][1024], B = wqkv [3072][1024]  (col block 0 -> Q via w_k, 1 -> K via w_q, 2 -> V)
  gemm_nt<<<dim3(32, 24), 256, 0, stream>>>(xb, wqkv, 1024, 0, qb, kb, vtb, nullptr, nullptr);

  attn_kernel<<<dim3(512), 512, 0, stream>>>(qb, kb, vtb, ctxb);

  // out = ctx @ w_o^T + b_o
  gemm_nt<<<dim3(32, 8), 256, 0, stream>>>(ctxb, wob, 1024, 1, nullptr, nullptr, nullptr, b_o, out);
}

// Round 8
// 224.843 us; speedup vs baseline: 1.1232x; 1.1232x over previous
//
#include <hip/hip_runtime.h>
#include <hip/hip_bf16.h>

// MHA: x[2,2048,1024]; q = x@w_k^T (faithful swap), k = x@w_q^T, v = x@w_v^T
// scores = QK^T * (1/sqrt(1024)), causal mask, softmax, ctx = P@V
// out = ctx@w_o^T + b_o   (fp32 out)

typedef __attribute__((ext_vector_type(8))) short bf16x8;
typedef __attribute__((ext_vector_type(4))) float f32x4;

#define SEQ 2048
#define NHEAD 16
#define HD 64
#define M_TOT 4096   // B*L

static __device__ __forceinline__ unsigned short f2bf(float f) {
  unsigned int u = __float_as_uint(f);
  u += 0x7fff + ((u >> 16) & 1);          // RNE
  return (unsigned short)(u >> 16);
}
static __device__ __forceinline__ float bf2f(unsigned short u) {
  return __uint_as_float(((unsigned int)u) << 16);
}
static __device__ __forceinline__ unsigned int cvt_pk_bf16(float lo, float hi) {
  unsigned int r;
  asm("v_cvt_pk_bf16_f32 %0, %1, %2" : "=v"(r) : "v"(lo), "v"(hi));
  return r;   // bits[15:0]=bf16(lo), bits[31:16]=bf16(hi)
}

static __device__ __forceinline__ void gload16(const unsigned short* g, unsigned short* l) {
  __builtin_amdgcn_global_load_lds(
      (const __attribute__((address_space(1))) unsigned int*)g,
      (__attribute__((address_space(3))) unsigned int*)l, 16, 0, 0);
}

// ---------------- fp32 -> bf16 convert, 4 elems/thread ----------------
__global__ void cvt_kernel(const float* __restrict__ in, unsigned short* __restrict__ out, int n) {
  int i = (blockIdx.x * blockDim.x + threadIdx.x) * 4;
  if (i >= n) return;
  float4 v = *reinterpret_cast<const float4*>(in + i);
  ushort4 o;
  o.x = f2bf(v.x); o.y = f2bf(v.y); o.z = f2bf(v.z); o.w = f2bf(v.w);
  *reinterpret_cast<ushort4*>(out + i) = o;
}

// ---------------- NT GEMM: C[M,N] = A[M,K] * B[N,K]^T ----------------
// 128x128 tile, 4 waves (2x2), BK=64, m97-style 2-barrier loop.
// mode 0: scatter to qb/kb ([b][h][l][d]) and vtb ([b][h][d][l]), bf16
// mode 1: out[m*1024+n] = acc + bias[n], fp32
__global__ __launch_bounds__(256) void gemm_nt(
    const unsigned short* __restrict__ A,
    const unsigned short* __restrict__ B,
    int K, int mode,
    unsigned short* __restrict__ qb,
    unsigned short* __restrict__ kb,
    unsigned short* __restrict__ vtb,
    const float* __restrict__ bias,
    float* __restrict__ outf)
{
  __shared__ unsigned short lds_a[128 * 64];
  __shared__ unsigned short lds_b[128 * 64];
  const int t = threadIdx.x;
  const int wid = t >> 6;
  const int lane = t & 63;
  const int lr = lane & 15;
  const int lg = lane >> 4;
  const int tm = blockIdx.x * 128;
  const int tn = blockIdx.y * 128;
  const int wr = (wid >> 1) * 64;
  const int wc = (wid & 1) * 64;

  const unsigned short* Ab = A + (size_t)tm * K;
  const unsigned short* Bb = B + (size_t)tn * K;
  const int srow = wid * 8 + (lane >> 3);   // row within a 32-row chunk
  const int scol = (lane & 7) * 8;          // bf16 col (16B granules)

  f32x4 acc[4][4];
  #pragma unroll
  for (int i = 0; i < 4; ++i)
    #pragma unroll
    for (int j = 0; j < 4; ++j) acc[i][j] = (f32x4){0.f, 0.f, 0.f, 0.f};

  for (int k0 = 0; k0 < K; k0 += 64) {
    #pragma unroll
    for (int i = 0; i < 4; ++i) {
      gload16(Ab + (size_t)(i * 32 + srow) * K + k0 + scol, &lds_a[(i * 32 + wid * 8) * 64]);
      gload16(Bb + (size_t)(i * 32 + srow) * K + k0 + scol, &lds_b[(i * 32 + wid * 8) * 64]);
    }
    __syncthreads();
    #pragma unroll
    for (int kk = 0; kk < 2; ++kk) {
      bf16x8 af[4], bfr[4];
      #pragma unroll
      for (int mi = 0; mi < 4; ++mi)
        af[mi] = *reinterpret_cast<const bf16x8*>(&lds_a[(wr + mi * 16 + lr) * 64 + kk * 32 + lg * 8]);
      #pragma unroll
      for (int ni = 0; ni < 4; ++ni)
        bfr[ni] = *reinterpret_cast<const bf16x8*>(&lds_b[(wc + ni * 16 + lr) * 64 + kk * 32 + lg * 8]);
      #pragma unroll
      for (int mi = 0; mi < 4; ++mi)
        #pragma unroll
        for (int ni = 0; ni < 4; ++ni)
          acc[mi][ni] = __builtin_amdgcn_mfma_f32_16x16x32_bf16(af[mi], bfr[ni], acc[mi][ni], 0, 0, 0);
    }
    __syncthreads();
  }

  if (mode == 0) {
    #pragma unroll
    for (int mi = 0; mi < 4; ++mi)
      #pragma unroll
      for (int ni = 0; ni < 4; ++ni)
        #pragma unroll
        for (int r = 0; r < 4; ++r) {
          int gm = tm + wr + mi * 16 + lg * 4 + r;
          int gn = tn + wc + ni * 16 + lr;
          float v = acc[mi][ni][r];
          unsigned short bv = f2bf(v);
          int bb = gm >> 11, l = gm & 2047;
          int tsel = gn >> 10, o = gn & 1023;
          int h = o >> 6, d = o & 63;
          if (tsel == 0)      qb[(((size_t)(bb * NHEAD + h)) * SEQ + l) * HD + d] = bv;
          else if (tsel == 1) kb[(((size_t)(bb * NHEAD + h)) * SEQ + l) * HD + d] = bv;
          else                vtb[(((size_t)(bb * NHEAD + h)) * HD + d) * SEQ + l] = bv;
        }
  } else {
    #pragma unroll
    for (int mi = 0; mi < 4; ++mi)
      #pragma unroll
      for (int ni = 0; ni < 4; ++ni)
        #pragma unroll
        for (int r = 0; r < 4; ++r) {
          int gm = tm + wr + mi * 16 + lg * 4 + r;
          int gn = tn + wc + ni * 16 + lr;
          outf[(size_t)gm * 1024 + gn] = acc[mi][ni][r] + bias[gn];
        }
  }
}

// ------------- flash attention, causal, swapped-QK^T softmax -------------
// Grid 512 x 256 threads (4 waves). xcd = id&7 owns 4 (b,h) pairs; each
// block does q-tiles (31-pair, pair): exactly 33 KV iterations (balanced).
// Wave w owns q-rows [qtile*64+16w, +16). K/V^T tiles LDS-staged
// (global_load_lds w=16, XOR-swizzled via pre-swizzled source), dbuf.
// QK^T computed SWAPPED: s = mfma(K_frag, Q_frag) so each lane owns ONE
// q-row (q = qw+lr) with 16 in-lane P values (kv = ni*16+lg*4+r) ->
// softmax = in-lane tree + 2 shfl_xor; P->bf16 via v_cvt_pk_bf16_f32;
// P staged as 4x ds_write_b64; PV reads P rows as A-fragments (b128).
// Defer-max (THR=8): skip O/ls rescale unless running max grew by >8.
__global__ __launch_bounds__(256) void attn_kernel(
    const unsigned short* __restrict__ qb,
    const unsigned short* __restrict__ kb,
    const unsigned short* __restrict__ vtb,
    unsigned short* __restrict__ ctxb)
{
  __shared__ unsigned short kt_lds[2][64 * 64];
  __shared__ unsigned short vt_lds[2][64 * 64];
  __shared__ unsigned short p_lds[4][16 * 64];

  const int t = threadIdx.x;
  const int wid = t >> 6;
  const int lane = t & 63;
  const int lr = lane & 15;
  const int lg = lane >> 4;

  const int id = blockIdx.x;
  const int xcd = id & 7;
  const int chunk = id >> 3;              // 0..63
  const int bh = xcd * 4 + (chunk >> 4);  // 4 (b,h) pairs per XCD
  const int pair = chunk & 15;            // 0..15
  const int b = bh >> 4, h = bh & 15;

  const float csc = (1.0f / 32.0f) * 1.44269504f;  // 1/sqrt(1024) * log2(e)

  const unsigned short* Kp = kb + (size_t)bh * SEQ * HD;   // row kv, stride HD
  const unsigned short* Vp = vtb + (size_t)bh * HD * SEQ;  // row d,  stride SEQ
  const int sr_ = lane >> 3;   // 0..7: row within an 8-row wave chunk
  const int sg_ = lane & 7;    // 0..7: 16B granule

  auto stage = [&](int buf, int kv0) {
    #pragma unroll
    for (int i = 0; i < 2; ++i) {
      int r = i * 32 + wid * 8 + sr_;
      int g = sg_ ^ (r & 7);   // pre-swizzled source granule
      gload16(Kp + (size_t)(kv0 + r) * HD + g * 8, &kt_lds[buf][(i * 32 + wid * 8) * 64]);
      gload16(Vp + (size_t)r * SEQ + kv0 + g * 8, &vt_lds[buf][(i * 32 + wid * 8) * 64]);
    }
  };

  for (int ph = 0; ph < 2; ++ph) {
    const int qtile = ph ? pair : (31 - pair);
    const int qw = qtile * 64 + wid * 16;

    // Q fragments, scale folded in (B-operand of swapped QK^T)
    const unsigned short* Qp = qb + ((size_t)bh * SEQ + qw) * HD;
    bf16x8 aq[2];
    #pragma unroll
    for (int kk = 0; kk < 2; ++kk) {
      bf16x8 raw = *reinterpret_cast<const bf16x8*>(&Qp[lr * HD + kk * 32 + lg * 8]);
      #pragma unroll
      for (int j = 0; j < 8; ++j)
        aq[kk][j] = (short)f2bf(bf2f((unsigned short)raw[j]) * csc);
    }

    f32x4 oacc[4];
    #pragma unroll
    for (int ni = 0; ni < 4; ++ni) oacc[ni] = (f32x4){0.f, 0.f, 0.f, 0.f};
    float m_ = -INFINITY, ls = 0.f;   // softmax state for q-row qw+lr

    stage(0, 0);
    __syncthreads();
    int cur = 0;

    for (int kt = 0; kt <= qtile; ++kt) {
      const int kv0 = kt * 64;
      if (kt < qtile) stage(cur ^ 1, kv0 + 64);   // prefetch next tile

      // S^T = K Q^T (log2 domain): s4[ni][r] = S[q=qw+lr][kv0+ni*16+lg*4+r]
      const char* kbase = (const char*)&kt_lds[cur][0];
      f32x4 s4[4];
      #pragma unroll
      for (int ni = 0; ni < 4; ++ni) {
        int row = ni * 16 + lr;
        int xr = (row & 7) << 4;
        bf16x8 b0 = *reinterpret_cast<const bf16x8*>(kbase + (row * 128 + ((lg * 16) ^ xr)));
        bf16x8 b1 = *reinterpret_cast<const bf16x8*>(kbase + (row * 128 + ((64 + lg * 16) ^ xr)));
        s4[ni] = (f32x4){0.f, 0.f, 0.f, 0.f};
        s4[ni] = __builtin_amdgcn_mfma_f32_16x16x32_bf16(b0, aq[0], s4[ni], 0, 0, 0);
        s4[ni] = __builtin_amdgcn_mfma_f32_16x16x32_bf16(b1, aq[1], s4[ni], 0, 0, 0);
      }

      if (kt == qtile) {   // causal mask, diagonal tile only
        #pragma unroll
        for (int ni = 0; ni < 4; ++ni)
          #pragma unroll
          for (int r = 0; r < 4; ++r)
            if (ni * 16 + lg * 4 + r > wid * 16 + lr) s4[ni][r] = -INFINITY;
      }

      // row max: in-lane tree over 16, then fold lanes +-16, +-32
      float rmax;
      {
        float a0 = fmaxf(fmaxf(s4[0][0], s4[0][1]), fmaxf(s4[0][2], s4[0][3]));
        float a1 = fmaxf(fmaxf(s4[1][0], s4[1][1]), fmaxf(s4[1][2], s4[1][3]));
        float a2 = fmaxf(fmaxf(s4[2][0], s4[2][1]), fmaxf(s4[2][2], s4[2][3]));
        float a3 = fmaxf(fmaxf(s4[3][0], s4[3][1]), fmaxf(s4[3][2], s4[3][3]));
        rmax = fmaxf(fmaxf(a0, a1), fmaxf(a2, a3));
        rmax = fmaxf(rmax, __shfl_xor(rmax, 16));
        rmax = fmaxf(rmax, __shfl_xor(rmax, 32));
      }

      // defer-max: rescale only when max grew by > 8 (P bounded by 2^8)
      if (__any(rmax > m_ + 8.f)) {
        float mn = fmaxf(m_, rmax);
        float f = exp2f(m_ - mn);
        m_ = mn;
        ls *= f;
        #pragma unroll
        for (int r = 0; r < 4; ++r) {
          float fo = __shfl(f, lg * 4 + r);   // f for q-row qw+lg*4+r
          #pragma unroll
          for (int ni = 0; ni < 4; ++ni) oacc[ni][r] *= fo;
        }
      }

      // P = exp2(S - m), in-lane sum, pack to bf16, stage to LDS
      float p[4][4];
      float psum = 0.f;
      #pragma unroll
      for (int ni = 0; ni < 4; ++ni) {
        float t0 = exp2f(s4[ni][0] - m_);
        float t1 = exp2f(s4[ni][1] - m_);
        float t2 = exp2f(s4[ni][2] - m_);
        float t3 = exp2f(s4[ni][3] - m_);
        p[ni][0] = t0; p[ni][1] = t1; p[ni][2] = t2; p[ni][3] = t3;
        psum += (t0 + t1) + (t2 + t3);
      }
      psum += __shfl_xor(psum, 16);
      psum += __shfl_xor(psum, 32);
      ls += psum;

      char* pbase = (char*)&p_lds[wid][0];
      const int xq = (lr & 7) << 4;
      #pragma unroll
      for (int ni = 0; ni < 4; ++ni) {
        uint2 w;
        w.x = cvt_pk_bf16(p[ni][0], p[ni][1]);
        w.y = cvt_pk_bf16(p[ni][2], p[ni][3]);
        *reinterpret_cast<uint2*>(pbase + ((lr * 128 + ni * 32 + lg * 8) ^ xq)) = w;
      }

      // P fragments: A-operand rows q=lr, kv contiguous (wave-private LDS)
      bf16x8 pa0 = *reinterpret_cast<const bf16x8*>(pbase + ((lr * 128 + lg * 16) ^ xq));
      bf16x8 pa1 = *reinterpret_cast<const bf16x8*>(pbase + ((lr * 128 + 64 + lg * 16) ^ xq));

      // ctx += P V : B rows are d (V^T tile), K-contig in kv
      const char* vbase = (const char*)&vt_lds[cur][0];
      #pragma unroll
      for (int ni = 0; ni < 4; ++ni) {
        int row = ni * 16 + lr;
        int xr = (row & 7) << 4;
        bf16x8 v0 = *reinterpret_cast<const bf16x8*>(vbase + (row * 128 + ((lg * 16) ^ xr)));
        bf16x8 v1 = *reinterpret_cast<const bf16x8*>(vbase + (row * 128 + ((64 + lg * 16) ^ xr)));
        oacc[ni] = __builtin_amdgcn_mfma_f32_16x16x32_bf16(pa0, v0, oacc[ni], 0, 0, 0);
        oacc[ni] = __builtin_amdgcn_mfma_f32_16x16x32_bf16(pa1, v1, oacc[ni], 0, 0, 0);
      }

      __syncthreads();   // drains vmcnt: next tile staged; this buffer free
      cur ^= 1;
    }

    // write ctx [b][l][h*64+d] bf16 (ls for q-row qw+lg*4+r via shfl)
    #pragma unroll
    for (int r = 0; r < 4; ++r) {
      float inv = 1.0f / __shfl(ls, lg * 4 + r);
      int qr = qw + lg * 4 + r;
      #pragma unroll
      for (int ni = 0; ni < 4; ++ni) {
        int d = ni * 16 + lr;
        ctxb[((size_t)b * SEQ + qr) * 1024 + h * HD + d] = f2bf(oacc[ni][r] * inv);
      }
    }
  }
}

extern "C" void kernel_launch(void* const* d_in, const int* in_sizes, int n_in,
                              void* d_out, int out_size, void* d_ws, size_t ws_size,
                              hipStream_t stream) {
  const float* x   = (const float*)d_in[0];
  const float* w_k = (const float*)d_in[1];
  const float* w_q = (const float*)d_in[2];
  const float* w_v = (const float*)d_in[3];
  const float* w_o = (const float*)d_in[4];
  const float* b_o = (const float*)d_in[5];
  float* out = (float*)d_out;

  char* ws = (char*)d_ws;
  unsigned short* xb   = (unsigned short*)(ws + 0);          //  8 MB [4096][1024]
  unsigned short* wqkv = (unsigned short*)(ws + 8388608);    //  6 MB [3072][1024]  (w_k;w_q;w_v)
  unsigned short* wob  = (unsigned short*)(ws + 14680064);   //  2 MB [1024][1024]
  unsigned short* qb   = (unsigned short*)(ws + 16777216);   //  8 MB [b][h][l][d]
  unsigned short* kb   = (unsigned short*)(ws + 25165824);   //  8 MB [b][h][l][d]
  unsigned short* vtb  = (unsigned short*)(ws + 33554432);   //  8 MB [b][h][d][l]
  unsigned short* ctxb = xb;                                  // reuse x region

  int n = M_TOT * 1024;
  cvt_kernel<<<n / 1024, 256, 0, stream>>>(x, xb, n);
  n = 1024 * 1024;
  cvt_kernel<<<n / 1024, 256, 0, stream>>>(w_k, wqkv, n);
  cvt_kernel<<<n / 1024, 256, 0, stream>>>(w_q, wqkv + 1048576, n);
  cvt_kernel<<<n / 1024, 256, 0, stream>>>(w_v, wqkv + 2097152, n);
  cvt_kernel<<<n / 1024, 256, 0, stream>>>(w_o, wob, n);

  // QKV: A = xb [4096][1024], B = wqkv [3072][1024]  (col block 0 -> Q via w_k, 1 -> K via w_q, 2 -> V)
  gemm_nt<<<dim3(32, 24), 256, 0, stream>>>(xb, wqkv, 1024, 0, qb, kb, vtb, nullptr, nullptr);

  attn_kernel<<<dim3(512), 256, 0, stream>>>(qb, kb, vtb, ctxb);

  // out = ctx @ w_o^T + b_o
  gemm_nt<<<dim3(32, 8), 256, 0, stream>>>(ctxb, wob, 1024, 1, nullptr, nullptr, nullptr, b_o, out);
}

// Round 9
// 217.270 us; speedup vs baseline: 1.1624x; 1.0349x over previous
//
#include <hip/hip_runtime.h>
#include <hip/hip_bf16.h>

// MHA: x[2,2048,1024]; q = x@w_k^T (faithful swap), k = x@w_q^T, v = x@w_v^T
// scores = QK^T * (1/sqrt(1024)), causal mask, softmax, ctx = P@V
// out = ctx@w_o^T + b_o   (fp32 out)

typedef __attribute__((ext_vector_type(8))) short bf16x8;
typedef __attribute__((ext_vector_type(4))) float f32x4;

#define SEQ 2048
#define NHEAD 16
#define HD 64
#define M_TOT 4096   // B*L

static __device__ __forceinline__ unsigned short f2bf(float f) {
  unsigned int u = __float_as_uint(f);
  u += 0x7fff + ((u >> 16) & 1);          // RNE
  return (unsigned short)(u >> 16);
}
static __device__ __forceinline__ float bf2f(unsigned short u) {
  return __uint_as_float(((unsigned int)u) << 16);
}
static __device__ __forceinline__ unsigned int cvt_pk_bf16(float lo, float hi) {
  unsigned int r;
  asm("v_cvt_pk_bf16_f32 %0, %1, %2" : "=v"(r) : "v"(lo), "v"(hi));
  return r;   // bits[15:0]=bf16(lo), bits[31:16]=bf16(hi)
}

static __device__ __forceinline__ void gload16(const unsigned short* g, unsigned short* l) {
  __builtin_amdgcn_global_load_lds(
      (const __attribute__((address_space(1))) unsigned int*)g,
      (__attribute__((address_space(3))) unsigned int*)l, 16, 0, 0);
}

// ---------------- fp32 -> bf16 convert, 4 elems/thread ----------------
__global__ void cvt_kernel(const float* __restrict__ in, unsigned short* __restrict__ out, int n) {
  int i = (blockIdx.x * blockDim.x + threadIdx.x) * 4;
  if (i >= n) return;
  float4 v = *reinterpret_cast<const float4*>(in + i);
  ushort4 o;
  o.x = f2bf(v.x); o.y = f2bf(v.y); o.z = f2bf(v.z); o.w = f2bf(v.w);
  *reinterpret_cast<ushort4*>(out + i) = o;
}

// 4 weight tensors (1M elems each) in one launch; blockIdx.y selects tensor.
__global__ void cvt4_kernel(const float* __restrict__ w0, const float* __restrict__ w1,
                            const float* __restrict__ w2, const float* __restrict__ w3,
                            unsigned short* __restrict__ o0, unsigned short* __restrict__ o1,
                            unsigned short* __restrict__ o2, unsigned short* __restrict__ o3) {
  const float* in; unsigned short* out;
  switch (blockIdx.y) {
    case 0: in = w0; out = o0; break;
    case 1: in = w1; out = o1; break;
    case 2: in = w2; out = o2; break;
    default: in = w3; out = o3; break;
  }
  int i = (blockIdx.x * blockDim.x + threadIdx.x) * 4;
  float4 v = *reinterpret_cast<const float4*>(in + i);
  ushort4 o;
  o.x = f2bf(v.x); o.y = f2bf(v.y); o.z = f2bf(v.z); o.w = f2bf(v.w);
  *reinterpret_cast<ushort4*>(out + i) = o;
}

// ---------------- NT GEMM: C[M,N] = A[M,K] * B[N,K]^T ----------------
// 128xBN tile, 4 waves (2x2), BK=64, m97-style 2-barrier loop.
// BN=96 -> QKV (grid 32x32 = 1024 blocks = 4/CU balanced, LDS 28KB)
// BN=64 -> O-proj (grid 32x16 = 512 blocks = 2/CU, LDS 24KB)
// MODE 0: scatter to qb/kb ([b][h][l][d]) and vtb ([b][h][d][l]), bf16
// MODE 1: out[m*1024+n] = acc + bias[n], fp32
template <int BN, int MODE>
__global__ __launch_bounds__(256) void gemm_tile(
    const unsigned short* __restrict__ A,
    const unsigned short* __restrict__ B,
    int K,
    unsigned short* __restrict__ qb,
    unsigned short* __restrict__ kb,
    unsigned short* __restrict__ vtb,
    const float* __restrict__ bias,
    float* __restrict__ outf)
{
  constexpr int NFR = BN / 32;              // N-frags per wave (wave cols = BN/2)
  __shared__ unsigned short lds_a[128 * 64];
  __shared__ unsigned short lds_b[BN * 64];
  const int t = threadIdx.x;
  const int wid = t >> 6;
  const int lane = t & 63;
  const int lr = lane & 15;
  const int lg = lane >> 4;
  const int tm = blockIdx.x * 128;
  const int tn = blockIdx.y * BN;
  const int wr = (wid >> 1) * 64;
  const int wc = (wid & 1) * (BN / 2);

  const unsigned short* Ab = A + (size_t)tm * K;
  const unsigned short* Bb = B + (size_t)tn * K;
  const int srow = wid * 8 + (lane >> 3);   // row within a 32-row chunk
  const int scol = (lane & 7) * 8;          // bf16 col (16B granules)

  f32x4 acc[4][NFR];
  #pragma unroll
  for (int i = 0; i < 4; ++i)
    #pragma unroll
    for (int j = 0; j < NFR; ++j) acc[i][j] = (f32x4){0.f, 0.f, 0.f, 0.f};

  for (int k0 = 0; k0 < K; k0 += 64) {
    #pragma unroll
    for (int i = 0; i < 4; ++i)
      gload16(Ab + (size_t)(i * 32 + srow) * K + k0 + scol, &lds_a[(i * 32 + wid * 8) * 64]);
    #pragma unroll
    for (int i = 0; i < NFR; ++i)
      gload16(Bb + (size_t)(i * 32 + srow) * K + k0 + scol, &lds_b[(i * 32 + wid * 8) * 64]);
    __syncthreads();
    #pragma unroll
    for (int kk = 0; kk < 2; ++kk) {
      bf16x8 af[4], bfr[NFR];
      #pragma unroll
      for (int mi = 0; mi < 4; ++mi)
        af[mi] = *reinterpret_cast<const bf16x8*>(&lds_a[(wr + mi * 16 + lr) * 64 + kk * 32 + lg * 8]);
      #pragma unroll
      for (int ni = 0; ni < NFR; ++ni)
        bfr[ni] = *reinterpret_cast<const bf16x8*>(&lds_b[(wc + ni * 16 + lr) * 64 + kk * 32 + lg * 8]);
      #pragma unroll
      for (int mi = 0; mi < 4; ++mi)
        #pragma unroll
        for (int ni = 0; ni < NFR; ++ni)
          acc[mi][ni] = __builtin_amdgcn_mfma_f32_16x16x32_bf16(af[mi], bfr[ni], acc[mi][ni], 0, 0, 0);
    }
    __syncthreads();
  }

  if (MODE == 0) {
    #pragma unroll
    for (int mi = 0; mi < 4; ++mi)
      #pragma unroll
      for (int ni = 0; ni < NFR; ++ni)
        #pragma unroll
        for (int r = 0; r < 4; ++r) {
          int gm = tm + wr + mi * 16 + lg * 4 + r;
          int gn = tn + wc + ni * 16 + lr;
          float v = acc[mi][ni][r];
          unsigned short bv = f2bf(v);
          int bb = gm >> 11, l = gm & 2047;
          int tsel = gn >> 10, o = gn & 1023;
          int h = o >> 6, d = o & 63;
          if (tsel == 0)      qb[(((size_t)(bb * NHEAD + h)) * SEQ + l) * HD + d] = bv;
          else if (tsel == 1) kb[(((size_t)(bb * NHEAD + h)) * SEQ + l) * HD + d] = bv;
          else                vtb[(((size_t)(bb * NHEAD + h)) * HD + d) * SEQ + l] = bv;
        }
  } else {
    #pragma unroll
    for (int mi = 0; mi < 4; ++mi)
      #pragma unroll
      for (int ni = 0; ni < NFR; ++ni)
        #pragma unroll
        for (int r = 0; r < 4; ++r) {
          int gm = tm + wr + mi * 16 + lg * 4 + r;
          int gn = tn + wc + ni * 16 + lr;
          outf[(size_t)gm * 1024 + gn] = acc[mi][ni][r] + bias[gn];
        }
  }
}

// ------------- flash attention, causal, swapped-QK^T softmax -------------
// Grid 512 x 256 threads (4 waves). xcd = id&7 owns 4 (b,h) pairs; each
// block does q-tiles (31-pair, pair): exactly 33 KV iterations (balanced).
// Wave w owns q-rows [qtile*64+16w, +16). K/V^T tiles LDS-staged
// (global_load_lds w=16, XOR-swizzled via pre-swizzled source), dbuf.
// QK^T computed SWAPPED: s = mfma(K_frag, Q_frag) so each lane owns ONE
// q-row (q = qw+lr) with 16 in-lane P values (kv = ni*16+lg*4+r) ->
// softmax = in-lane tree + 2 shfl_xor; P->bf16 via v_cvt_pk_bf16_f32;
// P staged as 4x ds_write_b64; PV reads P rows as A-fragments (b128).
// Defer-max (THR=8): skip O/ls rescale unless running max grew by >8.
__global__ __launch_bounds__(256) void attn_kernel(
    const unsigned short* __restrict__ qb,
    const unsigned short* __restrict__ kb,
    const unsigned short* __restrict__ vtb,
    unsigned short* __restrict__ ctxb)
{
  __shared__ unsigned short kt_lds[2][64 * 64];
  __shared__ unsigned short vt_lds[2][64 * 64];
  __shared__ unsigned short p_lds[4][16 * 64];

  const int t = threadIdx.x;
  const int wid = t >> 6;
  const int lane = t & 63;
  const int lr = lane & 15;
  const int lg = lane >> 4;

  const int id = blockIdx.x;
  const int xcd = id & 7;
  const int chunk = id >> 3;              // 0..63
  const int bh = xcd * 4 + (chunk >> 4);  // 4 (b,h) pairs per XCD
  const int pair = chunk & 15;            // 0..15
  const int b = bh >> 4, h = bh & 15;

  const float csc = (1.0f / 32.0f) * 1.44269504f;  // 1/sqrt(1024) * log2(e)

  const unsigned short* Kp = kb + (size_t)bh * SEQ * HD;   // row kv, stride HD
  const unsigned short* Vp = vtb + (size_t)bh * HD * SEQ;  // row d,  stride SEQ
  const int sr_ = lane >> 3;   // 0..7: row within an 8-row wave chunk
  const int sg_ = lane & 7;    // 0..7: 16B granule

  auto stage = [&](int buf, int kv0) {
    #pragma unroll
    for (int i = 0; i < 2; ++i) {
      int r = i * 32 + wid * 8 + sr_;
      int g = sg_ ^ (r & 7);   // pre-swizzled source granule
      gload16(Kp + (size_t)(kv0 + r) * HD + g * 8, &kt_lds[buf][(i * 32 + wid * 8) * 64]);
      gload16(Vp + (size_t)r * SEQ + kv0 + g * 8, &vt_lds[buf][(i * 32 + wid * 8) * 64]);
    }
  };

  for (int ph = 0; ph < 2; ++ph) {
    const int qtile = ph ? pair : (31 - pair);
    const int qw = qtile * 64 + wid * 16;

    // Q fragments, scale folded in (B-operand of swapped QK^T)
    const unsigned short* Qp = qb + ((size_t)bh * SEQ + qw) * HD;
    bf16x8 aq[2];
    #pragma unroll
    for (int kk = 0; kk < 2; ++kk) {
      bf16x8 raw = *reinterpret_cast<const bf16x8*>(&Qp[lr * HD + kk * 32 + lg * 8]);
      #pragma unroll
      for (int j = 0; j < 8; ++j)
        aq[kk][j] = (short)f2bf(bf2f((unsigned short)raw[j]) * csc);
    }

    f32x4 oacc[4];
    #pragma unroll
    for (int ni = 0; ni < 4; ++ni) oacc[ni] = (f32x4){0.f, 0.f, 0.f, 0.f};
    float m_ = -INFINITY, ls = 0.f;   // softmax state for q-row qw+lr

    stage(0, 0);
    __syncthreads();
    int cur = 0;

    for (int kt = 0; kt <= qtile; ++kt) {
      const int kv0 = kt * 64;
      if (kt < qtile) stage(cur ^ 1, kv0 + 64);   // prefetch next tile

      // S^T = K Q^T (log2 domain): s4[ni][r] = S[q=qw+lr][kv0+ni*16+lg*4+r]
      const char* kbase = (const char*)&kt_lds[cur][0];
      f32x4 s4[4];
      #pragma unroll
      for (int ni = 0; ni < 4; ++ni) {
        int row = ni * 16 + lr;
        int xr = (row & 7) << 4;
        bf16x8 b0 = *reinterpret_cast<const bf16x8*>(kbase + (row * 128 + ((lg * 16) ^ xr)));
        bf16x8 b1 = *reinterpret_cast<const bf16x8*>(kbase + (row * 128 + ((64 + lg * 16) ^ xr)));
        s4[ni] = (f32x4){0.f, 0.f, 0.f, 0.f};
        s4[ni] = __builtin_amdgcn_mfma_f32_16x16x32_bf16(b0, aq[0], s4[ni], 0, 0, 0);
        s4[ni] = __builtin_amdgcn_mfma_f32_16x16x32_bf16(b1, aq[1], s4[ni], 0, 0, 0);
      }

      if (kt == qtile) {   // causal mask, diagonal tile only
        #pragma unroll
        for (int ni = 0; ni < 4; ++ni)
          #pragma unroll
          for (int r = 0; r < 4; ++r)
            if (ni * 16 + lg * 4 + r > wid * 16 + lr) s4[ni][r] = -INFINITY;
      }

      // row max: in-lane tree over 16, then fold lanes +-16, +-32
      float rmax;
      {
        float a0 = fmaxf(fmaxf(s4[0][0], s4[0][1]), fmaxf(s4[0][2], s4[0][3]));
        float a1 = fmaxf(fmaxf(s4[1][0], s4[1][1]), fmaxf(s4[1][2], s4[1][3]));
        float a2 = fmaxf(fmaxf(s4[2][0], s4[2][1]), fmaxf(s4[2][2], s4[2][3]));
        float a3 = fmaxf(fmaxf(s4[3][0], s4[3][1]), fmaxf(s4[3][2], s4[3][3]));
        rmax = fmaxf(fmaxf(a0, a1), fmaxf(a2, a3));
        rmax = fmaxf(rmax, __shfl_xor(rmax, 16));
        rmax = fmaxf(rmax, __shfl_xor(rmax, 32));
      }

      // defer-max: rescale only when max grew by > 8 (P bounded by 2^8)
      if (__any(rmax > m_ + 8.f)) {
        float mn = fmaxf(m_, rmax);
        float f = exp2f(m_ - mn);
        m_ = mn;
        ls *= f;
        #pragma unroll
        for (int r = 0; r < 4; ++r) {
          float fo = __shfl(f, lg * 4 + r);   // f for q-row qw+lg*4+r
          #pragma unroll
          for (int ni = 0; ni < 4; ++ni) oacc[ni][r] *= fo;
        }
      }

      // P = exp2(S - m), in-lane sum, pack to bf16, stage to LDS
      float p[4][4];
      float psum = 0.f;
      #pragma unroll
      for (int ni = 0; ni < 4; ++ni) {
        float t0 = exp2f(s4[ni][0] - m_);
        float t1 = exp2f(s4[ni][1] - m_);
        float t2 = exp2f(s4[ni][2] - m_);
        float t3 = exp2f(s4[ni][3] - m_);
        p[ni][0] = t0; p[ni][1] = t1; p[ni][2] = t2; p[ni][3] = t3;
        psum += (t0 + t1) + (t2 + t3);
      }
      psum += __shfl_xor(psum, 16);
      psum += __shfl_xor(psum, 32);
      ls += psum;

      char* pbase = (char*)&p_lds[wid][0];
      const int xq = (lr & 7) << 4;
      #pragma unroll
      for (int ni = 0; ni < 4; ++ni) {
        uint2 w;
        w.x = cvt_pk_bf16(p[ni][0], p[ni][1]);
        w.y = cvt_pk_bf16(p[ni][2], p[ni][3]);
        *reinterpret_cast<uint2*>(pbase + ((lr * 128 + ni * 32 + lg * 8) ^ xq)) = w;
      }

      // P fragments: A-operand rows q=lr, kv contiguous (wave-private LDS)
      bf16x8 pa0 = *reinterpret_cast<const bf16x8*>(pbase + ((lr * 128 + lg * 16) ^ xq));
      bf16x8 pa1 = *reinterpret_cast<const bf16x8*>(pbase + ((lr * 128 + 64 + lg * 16) ^ xq));

      // ctx += P V : B rows are d (V^T tile), K-contig in kv
      const char* vbase = (const char*)&vt_lds[cur][0];
      #pragma unroll
      for (int ni = 0; ni < 4; ++ni) {
        int row = ni * 16 + lr;
        int xr = (row & 7) << 4;
        bf16x8 v0 = *reinterpret_cast<const bf16x8*>(vbase + (row * 128 + ((lg * 16) ^ xr)));
        bf16x8 v1 = *reinterpret_cast<const bf16x8*>(vbase + (row * 128 + ((64 + lg * 16) ^ xr)));
        oacc[ni] = __builtin_amdgcn_mfma_f32_16x16x32_bf16(pa0, v0, oacc[ni], 0, 0, 0);
        oacc[ni] = __builtin_amdgcn_mfma_f32_16x16x32_bf16(pa1, v1, oacc[ni], 0, 0, 0);
      }

      __syncthreads();   // drains vmcnt: next tile staged; this buffer free
      cur ^= 1;
    }

    // write ctx [b][l][h*64+d] bf16 (ls for q-row qw+lg*4+r via shfl)
    #pragma unroll
    for (int r = 0; r < 4; ++r) {
      float inv = 1.0f / __shfl(ls, lg * 4 + r);
      int qr = qw + lg * 4 + r;
      #pragma unroll
      for (int ni = 0; ni < 4; ++ni) {
        int d = ni * 16 + lr;
        ctxb[((size_t)b * SEQ + qr) * 1024 + h * HD + d] = f2bf(oacc[ni][r] * inv);
      }
    }
  }
}

extern "C" void kernel_launch(void* const* d_in, const int* in_sizes, int n_in,
                              void* d_out, int out_size, void* d_ws, size_t ws_size,
                              hipStream_t stream) {
  const float* x   = (const float*)d_in[0];
  const float* w_k = (const float*)d_in[1];
  const float* w_q = (const float*)d_in[2];
  const float* w_v = (const float*)d_in[3];
  const float* w_o = (const float*)d_in[4];
  const float* b_o = (const float*)d_in[5];
  float* out = (float*)d_out;

  char* ws = (char*)d_ws;
  unsigned short* xb   = (unsigned short*)(ws + 0);          //  8 MB [4096][1024]
  unsigned short* wqkv = (unsigned short*)(ws + 8388608);    //  6 MB [3072][1024]  (w_k;w_q;w_v)
  unsigned short* wob  = (unsigned short*)(ws + 14680064);   //  2 MB [1024][1024]
  unsigned short* qb   = (unsigned short*)(ws + 16777216);   //  8 MB [b][h][l][d]
  unsigned short* kb   = (unsigned short*)(ws + 25165824);   //  8 MB [b][h][l][d]
  unsigned short* vtb  = (unsigned short*)(ws + 33554432);   //  8 MB [b][h][d][l]
  unsigned short* ctxb = xb;                                  // reuse x region

  int n = M_TOT * 1024;
  cvt_kernel<<<n / 1024, 256, 0, stream>>>(x, xb, n);
  cvt4_kernel<<<dim3(1024, 4), 256, 0, stream>>>(
      w_k, w_q, w_v, w_o, wqkv, wqkv + 1048576, wqkv + 2097152, wob);

  // QKV: A = xb [4096][1024], B = wqkv [3072][1024]; 128x96 tiles, 1024 blocks
  gemm_tile<96, 0><<<dim3(32, 32), 256, 0, stream>>>(
      xb, wqkv, 1024, qb, kb, vtb, nullptr, nullptr);

  attn_kernel<<<dim3(512), 256, 0, stream>>>(qb, kb, vtb, ctxb);

  // out = ctx @ w_o^T + b_o ; 128x64 tiles, 512 blocks
  gemm_tile<64, 1><<<dim3(32, 16), 256, 0, stream>>>(
      ctxb, wob, 1024, nullptr, nullptr, nullptr, b_o, out);
}

// Round 10
// 200.954 us; speedup vs baseline: 1.2567x; 1.0812x over previous
//
#include <hip/hip_runtime.h>
#include <hip/hip_bf16.h>

// MHA: x[2,2048,1024]; q = x@w_k^T (faithful swap), k = x@w_q^T, v = x@w_v^T
// scores = QK^T * (1/sqrt(1024)), causal mask, softmax, ctx = P@V
// out = ctx@w_o^T + b_o   (fp32 out)

typedef __attribute__((ext_vector_type(8))) short bf16x8;
typedef __attribute__((ext_vector_type(4))) float f32x4;

#define SEQ 2048
#define NHEAD 16
#define HD 64
#define M_TOT 4096   // B*L

static __device__ __forceinline__ unsigned short f2bf(float f) {
  unsigned int u = __float_as_uint(f);
  u += 0x7fff + ((u >> 16) & 1);          // RNE
  return (unsigned short)(u >> 16);
}
static __device__ __forceinline__ float bf2f(unsigned short u) {
  return __uint_as_float(((unsigned int)u) << 16);
}
static __device__ __forceinline__ unsigned int cvt_pk_bf16(float lo, float hi) {
  unsigned int r;
  asm("v_cvt_pk_bf16_f32 %0, %1, %2" : "=v"(r) : "v"(lo), "v"(hi));
  return r;   // bits[15:0]=bf16(lo), bits[31:16]=bf16(hi)
}

static __device__ __forceinline__ void gload16(const unsigned short* g, unsigned short* l) {
  __builtin_amdgcn_global_load_lds(
      (const __attribute__((address_space(1))) unsigned int*)g,
      (__attribute__((address_space(3))) unsigned int*)l, 16, 0, 0);
}

// ---------------- fp32 -> bf16 convert, 4 elems/thread ----------------
__global__ void cvt_kernel(const float* __restrict__ in, unsigned short* __restrict__ out, int n) {
  int i = (blockIdx.x * blockDim.x + threadIdx.x) * 4;
  if (i >= n) return;
  float4 v = *reinterpret_cast<const float4*>(in + i);
  ushort4 o;
  o.x = f2bf(v.x); o.y = f2bf(v.y); o.z = f2bf(v.z); o.w = f2bf(v.w);
  *reinterpret_cast<ushort4*>(out + i) = o;
}

// 4 weight tensors (1M elems each) in one launch; blockIdx.y selects tensor.
__global__ void cvt4_kernel(const float* __restrict__ w0, const float* __restrict__ w1,
                            const float* __restrict__ w2, const float* __restrict__ w3,
                            unsigned short* __restrict__ o0, unsigned short* __restrict__ o1,
                            unsigned short* __restrict__ o2, unsigned short* __restrict__ o3) {
  const float* in; unsigned short* out;
  switch (blockIdx.y) {
    case 0: in = w0; out = o0; break;
    case 1: in = w1; out = o1; break;
    case 2: in = w2; out = o2; break;
    default: in = w3; out = o3; break;
  }
  int i = (blockIdx.x * blockDim.x + threadIdx.x) * 4;
  float4 v = *reinterpret_cast<const float4*>(in + i);
  ushort4 o;
  o.x = f2bf(v.x); o.y = f2bf(v.y); o.z = f2bf(v.z); o.w = f2bf(v.w);
  *reinterpret_cast<ushort4*>(out + i) = o;
}

// ---------------- NT GEMM: C[M,N] = A[M,K] * B[N,K]^T ----------------
// 128xBN tile, 4 waves (2x2), BK=64. 2-phase double-buffered schedule
// (T3-minimum): issue STAGE(next tile) BEFORE ds_read+MFMA of current;
// ONE barrier per K-step (its implicit vmcnt(0)+lgkmcnt(0) drains the
// prefetch after compute covered the latency). LDS XOR-swizzled both
// sides: pre-swizzled global source (granule g ^ (row&7)) + swizzled
// ds_read byte addr (col16B ^ ((row&7)<<4)) -> conflict-free b128 reads.
// BN=96 -> QKV (grid 32x32 = 1024 blocks, LDS 56KB, 2/CU, 2 rounds)
// BN=64 -> O-proj (grid 32x16 = 512 blocks, LDS 48KB, 2/CU, 1 round)
// MODE 0: scatter to qb/kb ([b][h][l][d]) and vtb ([b][h][d][l]), bf16
// MODE 1: out[m*1024+n] = acc + bias[n], fp32
template <int BN, int MODE>
__global__ __launch_bounds__(256) void gemm_tile(
    const unsigned short* __restrict__ A,
    const unsigned short* __restrict__ B,
    int K,
    unsigned short* __restrict__ qb,
    unsigned short* __restrict__ kb,
    unsigned short* __restrict__ vtb,
    const float* __restrict__ bias,
    float* __restrict__ outf)
{
  constexpr int NFR = BN / 32;              // N-frags per wave (wave cols = BN/2)
  __shared__ unsigned short lds_a[2][128 * 64];
  __shared__ unsigned short lds_b[2][BN * 64];
  const int t = threadIdx.x;
  const int wid = t >> 6;
  const int lane = t & 63;
  const int lr = lane & 15;
  const int lg = lane >> 4;
  const int tm = blockIdx.x * 128;
  const int tn = blockIdx.y * BN;
  const int wr = (wid >> 1) * 64;
  const int wc = (wid & 1) * (BN / 2);

  const unsigned short* Ab = A + (size_t)tm * K;
  const unsigned short* Bb = B + (size_t)tn * K;
  const int sr_ = lane >> 3;   // 0..7 row within 8-row wave chunk
  const int sg_ = lane & 7;    // 0..7 16B granule

  // stage one K-tile (A:128 rows, B:BN rows) into buf, pre-swizzled source
  auto stageA = [&](int buf, int k0) {
    #pragma unroll
    for (int i = 0; i < 4; ++i) {
      int r = i * 32 + wid * 8 + sr_;
      int g = sg_ ^ (r & 7);
      gload16(Ab + (size_t)r * K + k0 + g * 8, &lds_a[buf][(i * 32 + wid * 8) * 64]);
    }
  };
  auto stageB = [&](int buf, int k0) {
    #pragma unroll
    for (int i = 0; i < NFR; ++i) {
      int r = i * 32 + wid * 8 + sr_;
      int g = sg_ ^ (r & 7);
      gload16(Bb + (size_t)r * K + k0 + g * 8, &lds_b[buf][(i * 32 + wid * 8) * 64]);
    }
  };

  f32x4 acc[4][NFR];
  #pragma unroll
  for (int i = 0; i < 4; ++i)
    #pragma unroll
    for (int j = 0; j < NFR; ++j) acc[i][j] = (f32x4){0.f, 0.f, 0.f, 0.f};

  stageA(0, 0); stageB(0, 0);
  __syncthreads();                     // drains prologue stage
  int cur = 0;
  const int nks = K >> 6;

  for (int ks = 0; ks < nks; ++ks) {
    if (ks + 1 < nks) {                // prefetch next tile into other buffer
      stageA(cur ^ 1, (ks + 1) * 64);
      stageB(cur ^ 1, (ks + 1) * 64);
    }
    const char* abase = (const char*)&lds_a[cur][0];
    const char* bbase = (const char*)&lds_b[cur][0];
    #pragma unroll
    for (int kk = 0; kk < 2; ++kk) {
      bf16x8 af[4], bfr[NFR];
      #pragma unroll
      for (int mi = 0; mi < 4; ++mi) {
        int row = wr + mi * 16 + lr;
        af[mi] = *reinterpret_cast<const bf16x8*>(
            abase + row * 128 + ((kk * 64 + lg * 16) ^ ((row & 7) << 4)));
      }
      #pragma unroll
      for (int ni = 0; ni < NFR; ++ni) {
        int row = wc + ni * 16 + lr;
        bfr[ni] = *reinterpret_cast<const bf16x8*>(
            bbase + row * 128 + ((kk * 64 + lg * 16) ^ ((row & 7) << 4)));
      }
      #pragma unroll
      for (int mi = 0; mi < 4; ++mi)
        #pragma unroll
        for (int ni = 0; ni < NFR; ++ni)
          acc[mi][ni] = __builtin_amdgcn_mfma_f32_16x16x32_bf16(af[mi], bfr[ni], acc[mi][ni], 0, 0, 0);
    }
    __syncthreads();   // all reads of buf[cur] done; prefetch drained (vmcnt 0)
    cur ^= 1;
  }

  if (MODE == 0) {
    #pragma unroll
    for (int mi = 0; mi < 4; ++mi)
      #pragma unroll
      for (int ni = 0; ni < NFR; ++ni)
        #pragma unroll
        for (int r = 0; r < 4; ++r) {
          int gm = tm + wr + mi * 16 + lg * 4 + r;
          int gn = tn + wc + ni * 16 + lr;
          float v = acc[mi][ni][r];
          unsigned short bv = f2bf(v);
          int bb = gm >> 11, l = gm & 2047;
          int tsel = gn >> 10, o = gn & 1023;
          int h = o >> 6, d = o & 63;
          if (tsel == 0)      qb[(((size_t)(bb * NHEAD + h)) * SEQ + l) * HD + d] = bv;
          else if (tsel == 1) kb[(((size_t)(bb * NHEAD + h)) * SEQ + l) * HD + d] = bv;
          else                vtb[(((size_t)(bb * NHEAD + h)) * HD + d) * SEQ + l] = bv;
        }
  } else {
    #pragma unroll
    for (int mi = 0; mi < 4; ++mi)
      #pragma unroll
      for (int ni = 0; ni < NFR; ++ni)
        #pragma unroll
        for (int r = 0; r < 4; ++r) {
          int gm = tm + wr + mi * 16 + lg * 4 + r;
          int gn = tn + wc + ni * 16 + lr;
          outf[(size_t)gm * 1024 + gn] = acc[mi][ni][r] + bias[gn];
        }
  }
}

// ------------- flash attention, causal, swapped-QK^T softmax -------------
// Grid 512 x 256 threads (4 waves). xcd = id&7 owns 4 (b,h) pairs; each
// block does q-tiles (31-pair, pair): exactly 33 KV iterations (balanced).
// Wave w owns q-rows [qtile*64+16w, +16). K/V^T tiles LDS-staged
// (global_load_lds w=16, XOR-swizzled via pre-swizzled source), dbuf.
// QK^T computed SWAPPED: s = mfma(K_frag, Q_frag) so each lane owns ONE
// q-row (q = qw+lr) with 16 in-lane P values (kv = ni*16+lg*4+r) ->
// softmax = in-lane tree + 2 shfl_xor; P->bf16 via v_cvt_pk_bf16_f32;
// P staged as 4x ds_write_b64; PV reads P rows as A-fragments (b128).
// Defer-max (THR=8): skip O/ls rescale unless running max grew by >8.
__global__ __launch_bounds__(256) void attn_kernel(
    const unsigned short* __restrict__ qb,
    const unsigned short* __restrict__ kb,
    const unsigned short* __restrict__ vtb,
    unsigned short* __restrict__ ctxb)
{
  __shared__ unsigned short kt_lds[2][64 * 64];
  __shared__ unsigned short vt_lds[2][64 * 64];
  __shared__ unsigned short p_lds[4][16 * 64];

  const int t = threadIdx.x;
  const int wid = t >> 6;
  const int lane = t & 63;
  const int lr = lane & 15;
  const int lg = lane >> 4;

  const int id = blockIdx.x;
  const int xcd = id & 7;
  const int chunk = id >> 3;              // 0..63
  const int bh = xcd * 4 + (chunk >> 4);  // 4 (b,h) pairs per XCD
  const int pair = chunk & 15;            // 0..15
  const int b = bh >> 4, h = bh & 15;

  const float csc = (1.0f / 32.0f) * 1.44269504f;  // 1/sqrt(1024) * log2(e)

  const unsigned short* Kp = kb + (size_t)bh * SEQ * HD;   // row kv, stride HD
  const unsigned short* Vp = vtb + (size_t)bh * HD * SEQ;  // row d,  stride SEQ
  const int sr_ = lane >> 3;   // 0..7: row within an 8-row wave chunk
  const int sg_ = lane & 7;    // 0..7: 16B granule

  auto stage = [&](int buf, int kv0) {
    #pragma unroll
    for (int i = 0; i < 2; ++i) {
      int r = i * 32 + wid * 8 + sr_;
      int g = sg_ ^ (r & 7);   // pre-swizzled source granule
      gload16(Kp + (size_t)(kv0 + r) * HD + g * 8, &kt_lds[buf][(i * 32 + wid * 8) * 64]);
      gload16(Vp + (size_t)r * SEQ + kv0 + g * 8, &vt_lds[buf][(i * 32 + wid * 8) * 64]);
    }
  };

  for (int ph = 0; ph < 2; ++ph) {
    const int qtile = ph ? pair : (31 - pair);
    const int qw = qtile * 64 + wid * 16;

    // Q fragments, scale folded in (B-operand of swapped QK^T)
    const unsigned short* Qp = qb + ((size_t)bh * SEQ + qw) * HD;
    bf16x8 aq[2];
    #pragma unroll
    for (int kk = 0; kk < 2; ++kk) {
      bf16x8 raw = *reinterpret_cast<const bf16x8*>(&Qp[lr * HD + kk * 32 + lg * 8]);
      #pragma unroll
      for (int j = 0; j < 8; ++j)
        aq[kk][j] = (short)f2bf(bf2f((unsigned short)raw[j]) * csc);
    }

    f32x4 oacc[4];
    #pragma unroll
    for (int ni = 0; ni < 4; ++ni) oacc[ni] = (f32x4){0.f, 0.f, 0.f, 0.f};
    float m_ = -INFINITY, ls = 0.f;   // softmax state for q-row qw+lr

    stage(0, 0);
    __syncthreads();
    int cur = 0;

    for (int kt = 0; kt <= qtile; ++kt) {
      const int kv0 = kt * 64;
      if (kt < qtile) stage(cur ^ 1, kv0 + 64);   // prefetch next tile

      // S^T = K Q^T (log2 domain): s4[ni][r] = S[q=qw+lr][kv0+ni*16+lg*4+r]
      const char* kbase = (const char*)&kt_lds[cur][0];
      f32x4 s4[4];
      #pragma unroll
      for (int ni = 0; ni < 4; ++ni) {
        int row = ni * 16 + lr;
        int xr = (row & 7) << 4;
        bf16x8 b0 = *reinterpret_cast<const bf16x8*>(kbase + (row * 128 + ((lg * 16) ^ xr)));
        bf16x8 b1 = *reinterpret_cast<const bf16x8*>(kbase + (row * 128 + ((64 + lg * 16) ^ xr)));
        s4[ni] = (f32x4){0.f, 0.f, 0.f, 0.f};
        s4[ni] = __builtin_amdgcn_mfma_f32_16x16x32_bf16(b0, aq[0], s4[ni], 0, 0, 0);
        s4[ni] = __builtin_amdgcn_mfma_f32_16x16x32_bf16(b1, aq[1], s4[ni], 0, 0, 0);
      }

      if (kt == qtile) {   // causal mask, diagonal tile only
        #pragma unroll
        for (int ni = 0; ni < 4; ++ni)
          #pragma unroll
          for (int r = 0; r < 4; ++r)
            if (ni * 16 + lg * 4 + r > wid * 16 + lr) s4[ni][r] = -INFINITY;
      }

      // row max: in-lane tree over 16, then fold lanes +-16, +-32
      float rmax;
      {
        float a0 = fmaxf(fmaxf(s4[0][0], s4[0][1]), fmaxf(s4[0][2], s4[0][3]));
        float a1 = fmaxf(fmaxf(s4[1][0], s4[1][1]), fmaxf(s4[1][2], s4[1][3]));
        float a2 = fmaxf(fmaxf(s4[2][0], s4[2][1]), fmaxf(s4[2][2], s4[2][3]));
        float a3 = fmaxf(fmaxf(s4[3][0], s4[3][1]), fmaxf(s4[3][2], s4[3][3]));
        rmax = fmaxf(fmaxf(a0, a1), fmaxf(a2, a3));
        rmax = fmaxf(rmax, __shfl_xor(rmax, 16));
        rmax = fmaxf(rmax, __shfl_xor(rmax, 32));
      }

      // defer-max: rescale only when max grew by > 8 (P bounded by 2^8)
      if (__any(rmax > m_ + 8.f)) {
        float mn = fmaxf(m_, rmax);
        float f = exp2f(m_ - mn);
        m_ = mn;
        ls *= f;
        #pragma unroll
        for (int r = 0; r < 4; ++r) {
          float fo = __shfl(f, lg * 4 + r);   // f for q-row qw+lg*4+r
          #pragma unroll
          for (int ni = 0; ni < 4; ++ni) oacc[ni][r] *= fo;
        }
      }

      // P = exp2(S - m), in-lane sum, pack to bf16, stage to LDS
      float p[4][4];
      float psum = 0.f;
      #pragma unroll
      for (int ni = 0; ni < 4; ++ni) {
        float t0 = exp2f(s4[ni][0] - m_);
        float t1 = exp2f(s4[ni][1] - m_);
        float t2 = exp2f(s4[ni][2] - m_);
        float t3 = exp2f(s4[ni][3] - m_);
        p[ni][0] = t0; p[ni][1] = t1; p[ni][2] = t2; p[ni][3] = t3;
        psum += (t0 + t1) + (t2 + t3);
      }
      psum += __shfl_xor(psum, 16);
      psum += __shfl_xor(psum, 32);
      ls += psum;

      char* pbase = (char*)&p_lds[wid][0];
      const int xq = (lr & 7) << 4;
      #pragma unroll
      for (int ni = 0; ni < 4; ++ni) {
        uint2 w;
        w.x = cvt_pk_bf16(p[ni][0], p[ni][1]);
        w.y = cvt_pk_bf16(p[ni][2], p[ni][3]);
        *reinterpret_cast<uint2*>(pbase + ((lr * 128 + ni * 32 + lg * 8) ^ xq)) = w;
      }

      // P fragments: A-operand rows q=lr, kv contiguous (wave-private LDS)
      bf16x8 pa0 = *reinterpret_cast<const bf16x8*>(pbase + ((lr * 128 + lg * 16) ^ xq));
      bf16x8 pa1 = *reinterpret_cast<const bf16x8*>(pbase + ((lr * 128 + 64 + lg * 16) ^ xq));

      // ctx += P V : B rows are d (V^T tile), K-contig in kv
      const char* vbase = (const char*)&vt_lds[cur][0];
      #pragma unroll
      for (int ni = 0; ni < 4; ++ni) {
        int row = ni * 16 + lr;
        int xr = (row & 7) << 4;
        bf16x8 v0 = *reinterpret_cast<const bf16x8*>(vbase + (row * 128 + ((lg * 16) ^ xr)));
        bf16x8 v1 = *reinterpret_cast<const bf16x8*>(vbase + (row * 128 + ((64 + lg * 16) ^ xr)));
        oacc[ni] = __builtin_amdgcn_mfma_f32_16x16x32_bf16(pa0, v0, oacc[ni], 0, 0, 0);
        oacc[ni] = __builtin_amdgcn_mfma_f32_16x16x32_bf16(pa1, v1, oacc[ni], 0, 0, 0);
      }

      __syncthreads();   // drains vmcnt: next tile staged; this buffer free
      cur ^= 1;
    }

    // write ctx [b][l][h*64+d] bf16 (ls for q-row qw+lg*4+r via shfl)
    #pragma unroll
    for (int r = 0; r < 4; ++r) {
      float inv = 1.0f / __shfl(ls, lg * 4 + r);
      int qr = qw + lg * 4 + r;
      #pragma unroll
      for (int ni = 0; ni < 4; ++ni) {
        int d = ni * 16 + lr;
        ctxb[((size_t)b * SEQ + qr) * 1024 + h * HD + d] = f2bf(oacc[ni][r] * inv);
      }
    }
  }
}

extern "C" void kernel_launch(void* const* d_in, const int* in_sizes, int n_in,
                              void* d_out, int out_size, void* d_ws, size_t ws_size,
                              hipStream_t stream) {
  const float* x   = (const float*)d_in[0];
  const float* w_k = (const float*)d_in[1];
  const float* w_q = (const float*)d_in[2];
  const float* w_v = (const float*)d_in[3];
  const float* w_o = (const float*)d_in[4];
  const float* b_o = (const float*)d_in[5];
  float* out = (float*)d_out;

  char* ws = (char*)d_ws;
  unsigned short* xb   = (unsigned short*)(ws + 0);          //  8 MB [4096][1024]
  unsigned short* wqkv = (unsigned short*)(ws + 8388608);    //  6 MB [3072][1024]  (w_k;w_q;w_v)
  unsigned short* wob  = (unsigned short*)(ws + 14680064);   //  2 MB [1024][1024]
  unsigned short* qb   = (unsigned short*)(ws + 16777216);   //  8 MB [b][h][l][d]
  unsigned short* kb   = (unsigned short*)(ws + 25165824);   //  8 MB [b][h][l][d]
  unsigned short* vtb  = (unsigned short*)(ws + 33554432);   //  8 MB [b][h][d][l]
  unsigned short* ctxb = xb;                                  // reuse x region

  int n = M_TOT * 1024;
  cvt_kernel<<<n / 1024, 256, 0, stream>>>(x, xb, n);
  cvt4_kernel<<<dim3(1024, 4), 256, 0, stream>>>(
      w_k, w_q, w_v, w_o, wqkv, wqkv + 1048576, wqkv + 2097152, wob);

  // QKV: A = xb [4096][1024], B = wqkv [3072][1024]; 128x96 tiles, 1024 blocks
  gemm_tile<96, 0><<<dim3(32, 32), 256, 0, stream>>>(
      xb, wqkv, 1024, qb, kb, vtb, nullptr, nullptr);

  attn_kernel<<<dim3(512), 256, 0, stream>>>(qb, kb, vtb, ctxb);

  // out = ctx @ w_o^T + b_o ; 128x64 tiles, 512 blocks
  gemm_tile<64, 1><<<dim3(32, 16), 256, 0, stream>>>(
      ctxb, wob, 1024, nullptr, nullptr, nullptr, b_o, out);
}

// Round 12
// 196.358 us; speedup vs baseline: 1.2862x; 1.0234x over previous
//
#include <hip/hip_runtime.h>
#include <hip/hip_bf16.h>

// MHA: x[2,2048,1024]; q = x@w_k^T (faithful swap), k = x@w_q^T, v = x@w_v^T
// scores = QK^T * (1/sqrt(1024)), causal mask, softmax, ctx = P@V
// out = ctx@w_o^T + b_o   (fp32 out)

typedef __attribute__((ext_vector_type(8))) short bf16x8;
typedef __attribute__((ext_vector_type(4))) float f32x4;

#define SEQ 2048
#define NHEAD 16
#define HD 64
#define M_TOT 4096   // B*L

static __device__ __forceinline__ unsigned short f2bf(float f) {
  unsigned int u = __float_as_uint(f);
  u += 0x7fff + ((u >> 16) & 1);          // RNE
  return (unsigned short)(u >> 16);
}
static __device__ __forceinline__ float bf2f(unsigned short u) {
  return __uint_as_float(((unsigned int)u) << 16);
}
static __device__ __forceinline__ unsigned int cvt_pk_bf16(float lo, float hi) {
  unsigned int r;
  asm("v_cvt_pk_bf16_f32 %0, %1, %2" : "=v"(r) : "v"(lo), "v"(hi));
  return r;   // bits[15:0]=bf16(lo), bits[31:16]=bf16(hi)
}

static __device__ __forceinline__ void gload16(const unsigned short* g, unsigned short* l) {
  __builtin_amdgcn_global_load_lds(
      (const __attribute__((address_space(1))) unsigned int*)g,
      (__attribute__((address_space(3))) unsigned int*)l, 16, 0, 0);
}

// ---------------- fp32 -> bf16 convert, 4 elems/thread ----------------
__global__ void cvt_kernel(const float* __restrict__ in, unsigned short* __restrict__ out, int n) {
  int i = (blockIdx.x * blockDim.x + threadIdx.x) * 4;
  if (i >= n) return;
  float4 v = *reinterpret_cast<const float4*>(in + i);
  ushort4 o;
  o.x = f2bf(v.x); o.y = f2bf(v.y); o.z = f2bf(v.z); o.w = f2bf(v.w);
  *reinterpret_cast<ushort4*>(out + i) = o;
}

// 4 weight tensors (1M elems each) in one launch; blockIdx.y selects tensor.
__global__ void cvt4_kernel(const float* __restrict__ w0, const float* __restrict__ w1,
                            const float* __restrict__ w2, const float* __restrict__ w3,
                            unsigned short* __restrict__ o0, unsigned short* __restrict__ o1,
                            unsigned short* __restrict__ o2, unsigned short* __restrict__ o3) {
  const float* in; unsigned short* out;
  switch (blockIdx.y) {
    case 0: in = w0; out = o0; break;
    case 1: in = w1; out = o1; break;
    case 2: in = w2; out = o2; break;
    default: in = w3; out = o3; break;
  }
  int i = (blockIdx.x * blockDim.x + threadIdx.x) * 4;
  float4 v = *reinterpret_cast<const float4*>(in + i);
  ushort4 o;
  o.x = f2bf(v.x); o.y = f2bf(v.y); o.z = f2bf(v.z); o.w = f2bf(v.w);
  *reinterpret_cast<ushort4*>(out + i) = o;
}

// ---------------- NT GEMM: C[M,N] = A[M,K] * B[N,K]^T ----------------
// 128xBN tile, 4 waves (2x2), BK=64. 2-phase double-buffered schedule
// (T3-minimum): issue STAGE(next tile) BEFORE ds_read+MFMA of current;
// ONE barrier per K-step (its implicit vmcnt(0)+lgkmcnt(0) drains the
// prefetch after compute covered the latency). LDS XOR-swizzled both
// sides: pre-swizzled global source (granule g ^ (row&7)) + swizzled
// ds_read byte addr (col16B ^ ((row&7)<<4)) -> conflict-free b128 reads.
// BN=96 -> QKV (grid 32x32 = 1024 blocks, LDS 56KB, 2/CU, 2 rounds)
// BN=64 -> O-proj (grid 32x16 = 512 blocks, LDS 48KB, 2/CU, 1 round)
// MODE 0: scatter to qb/kb ([b][h][l][d]) and vtb ([b][h][d][l]), bf16
// MODE 1: out[m*1024+n] = acc + bias[n], fp32
template <int BN, int MODE>
__global__ __launch_bounds__(256) void gemm_tile(
    const unsigned short* __restrict__ A,
    const unsigned short* __restrict__ B,
    int K,
    unsigned short* __restrict__ qb,
    unsigned short* __restrict__ kb,
    unsigned short* __restrict__ vtb,
    const float* __restrict__ bias,
    float* __restrict__ outf)
{
  constexpr int NFR = BN / 32;              // N-frags per wave (wave cols = BN/2)
  __shared__ unsigned short lds_a[2][128 * 64];
  __shared__ unsigned short lds_b[2][BN * 64];
  const int t = threadIdx.x;
  const int wid = t >> 6;
  const int lane = t & 63;
  const int lr = lane & 15;
  const int lg = lane >> 4;
  const int tm = blockIdx.x * 128;
  const int tn = blockIdx.y * BN;
  const int wr = (wid >> 1) * 64;
  const int wc = (wid & 1) * (BN / 2);

  const unsigned short* Ab = A + (size_t)tm * K;
  const unsigned short* Bb = B + (size_t)tn * K;
  const int sr_ = lane >> 3;   // 0..7 row within 8-row wave chunk
  const int sg_ = lane & 7;    // 0..7 16B granule

  // stage one K-tile (A:128 rows, B:BN rows) into buf, pre-swizzled source
  auto stageA = [&](int buf, int k0) {
    #pragma unroll
    for (int i = 0; i < 4; ++i) {
      int r = i * 32 + wid * 8 + sr_;
      int g = sg_ ^ (r & 7);
      gload16(Ab + (size_t)r * K + k0 + g * 8, &lds_a[buf][(i * 32 + wid * 8) * 64]);
    }
  };
  auto stageB = [&](int buf, int k0) {
    #pragma unroll
    for (int i = 0; i < NFR; ++i) {
      int r = i * 32 + wid * 8 + sr_;
      int g = sg_ ^ (r & 7);
      gload16(Bb + (size_t)r * K + k0 + g * 8, &lds_b[buf][(i * 32 + wid * 8) * 64]);
    }
  };

  f32x4 acc[4][NFR];
  #pragma unroll
  for (int i = 0; i < 4; ++i)
    #pragma unroll
    for (int j = 0; j < NFR; ++j) acc[i][j] = (f32x4){0.f, 0.f, 0.f, 0.f};

  stageA(0, 0); stageB(0, 0);
  __syncthreads();                     // drains prologue stage
  int cur = 0;
  const int nks = K >> 6;

  for (int ks = 0; ks < nks; ++ks) {
    if (ks + 1 < nks) {                // prefetch next tile into other buffer
      stageA(cur ^ 1, (ks + 1) * 64);
      stageB(cur ^ 1, (ks + 1) * 64);
    }
    const char* abase = (const char*)&lds_a[cur][0];
    const char* bbase = (const char*)&lds_b[cur][0];
    #pragma unroll
    for (int kk = 0; kk < 2; ++kk) {
      bf16x8 af[4], bfr[NFR];
      #pragma unroll
      for (int mi = 0; mi < 4; ++mi) {
        int row = wr + mi * 16 + lr;
        af[mi] = *reinterpret_cast<const bf16x8*>(
            abase + row * 128 + ((kk * 64 + lg * 16) ^ ((row & 7) << 4)));
      }
      #pragma unroll
      for (int ni = 0; ni < NFR; ++ni) {
        int row = wc + ni * 16 + lr;
        bfr[ni] = *reinterpret_cast<const bf16x8*>(
            bbase + row * 128 + ((kk * 64 + lg * 16) ^ ((row & 7) << 4)));
      }
      #pragma unroll
      for (int mi = 0; mi < 4; ++mi)
        #pragma unroll
        for (int ni = 0; ni < NFR; ++ni)
          acc[mi][ni] = __builtin_amdgcn_mfma_f32_16x16x32_bf16(af[mi], bfr[ni], acc[mi][ni], 0, 0, 0);
    }
    __syncthreads();   // all reads of buf[cur] done; prefetch drained (vmcnt 0)
    cur ^= 1;
  }

  if (MODE == 0) {
    #pragma unroll
    for (int mi = 0; mi < 4; ++mi)
      #pragma unroll
      for (int ni = 0; ni < NFR; ++ni)
        #pragma unroll
        for (int r = 0; r < 4; ++r) {
          int gm = tm + wr + mi * 16 + lg * 4 + r;
          int gn = tn + wc + ni * 16 + lr;
          float v = acc[mi][ni][r];
          unsigned short bv = f2bf(v);
          int bb = gm >> 11, l = gm & 2047;
          int tsel = gn >> 10, o = gn & 1023;
          int h = o >> 6, d = o & 63;
          if (tsel == 0)      qb[(((size_t)(bb * NHEAD + h)) * SEQ + l) * HD + d] = bv;
          else if (tsel == 1) kb[(((size_t)(bb * NHEAD + h)) * SEQ + l) * HD + d] = bv;
          else                vtb[(((size_t)(bb * NHEAD + h)) * HD + d) * SEQ + l] = bv;
        }
  } else {
    #pragma unroll
    for (int mi = 0; mi < 4; ++mi)
      #pragma unroll
      for (int ni = 0; ni < NFR; ++ni)
        #pragma unroll
        for (int r = 0; r < 4; ++r) {
          int gm = tm + wr + mi * 16 + lg * 4 + r;
          int gn = tn + wc + ni * 16 + lr;
          outf[(size_t)gm * 1024 + gn] = acc[mi][ni][r] + bias[gn];
        }
  }
}

// ------------- flash attention, causal, swapped-QK^T softmax -------------
// Grid 1024 x 256 threads (4 waves): ONE q-tile per block. LPT dispatch:
// qtile = 31 - (id>>5) -> heavy tiles launch first, light tiles dynamically
// backfill CUs as they free (near-balanced makespan). bh = id&31 keeps the
// XCD mapping stable: XCD x only ever sees bh in {x, x+8, x+16, x+24}
// (K/V working set 2MB < 4MB L2). 40KB LDS -> 4 blocks/CU = 16 waves/CU.
// Wave w owns q-rows [qtile*64+16w, +16). K/V^T tiles LDS-staged
// (global_load_lds w=16, XOR-swizzled via pre-swizzled source), dbuf.
// QK^T computed SWAPPED: s = mfma(K_frag, Q_frag) so each lane owns ONE
// q-row (q = qw+lr) with 16 in-lane P values -> softmax = in-lane tree +
// 2 shfl_xor; P->bf16 via v_cvt_pk_bf16_f32; P staged as 4x ds_write_b64;
// PV reads P rows as A-fragments (b128). Defer-max (THR=8). T5 setprio
// around both MFMA clusters.
__global__ __launch_bounds__(256) void attn_kernel(
    const unsigned short* __restrict__ qb,
    const unsigned short* __restrict__ kb,
    const unsigned short* __restrict__ vtb,
    unsigned short* __restrict__ ctxb)
{
  __shared__ unsigned short kt_lds[2][64 * 64];
  __shared__ unsigned short vt_lds[2][64 * 64];
  __shared__ unsigned short p_lds[4][16 * 64];

  const int t = threadIdx.x;
  const int wid = t >> 6;
  const int lane = t & 63;
  const int lr = lane & 15;
  const int lg = lane >> 4;

  const int id = blockIdx.x;
  const int bh = id & 31;                 // XCD-stable: bh mod 8 == id mod 8
  const int qtile = 31 - (id >> 5);       // heavy-first (LPT)
  const int b = bh >> 4, h = bh & 15;
  const int qw = qtile * 64 + wid * 16;

  const float csc = (1.0f / 32.0f) * 1.44269504f;  // 1/sqrt(1024) * log2(e)

  const unsigned short* Kp = kb + (size_t)bh * SEQ * HD;   // row kv, stride HD
  const unsigned short* Vp = vtb + (size_t)bh * HD * SEQ;  // row d,  stride SEQ
  const int sr_ = lane >> 3;   // 0..7: row within an 8-row wave chunk
  const int sg_ = lane & 7;    // 0..7: 16B granule

  auto stage = [&](int buf, int kv0) {
    #pragma unroll
    for (int i = 0; i < 2; ++i) {
      int r = i * 32 + wid * 8 + sr_;
      int g = sg_ ^ (r & 7);   // pre-swizzled source granule
      gload16(Kp + (size_t)(kv0 + r) * HD + g * 8, &kt_lds[buf][(i * 32 + wid * 8) * 64]);
      gload16(Vp + (size_t)r * SEQ + kv0 + g * 8, &vt_lds[buf][(i * 32 + wid * 8) * 64]);
    }
  };

  // Q fragments, scale folded in (B-operand of swapped QK^T)
  const unsigned short* Qp = qb + ((size_t)bh * SEQ + qw) * HD;
  bf16x8 aq[2];
  #pragma unroll
  for (int kk = 0; kk < 2; ++kk) {
    bf16x8 raw = *reinterpret_cast<const bf16x8*>(&Qp[lr * HD + kk * 32 + lg * 8]);
    #pragma unroll
    for (int j = 0; j < 8; ++j)
      aq[kk][j] = (short)f2bf(bf2f((unsigned short)raw[j]) * csc);
  }

  f32x4 oacc[4];
  #pragma unroll
  for (int ni = 0; ni < 4; ++ni) oacc[ni] = (f32x4){0.f, 0.f, 0.f, 0.f};
  float m_ = -INFINITY, ls = 0.f;   // softmax state for q-row qw+lr

  stage(0, 0);
  __syncthreads();
  int cur = 0;

  for (int kt = 0; kt <= qtile; ++kt) {
    const int kv0 = kt * 64;
    if (kt < qtile) stage(cur ^ 1, kv0 + 64);   // prefetch next tile

    // S^T = K Q^T (log2 domain): s4[ni][r] = S[q=qw+lr][kv0+ni*16+lg*4+r]
    const char* kbase = (const char*)&kt_lds[cur][0];
    f32x4 s4[4];
    __builtin_amdgcn_s_setprio(1);
    #pragma unroll
    for (int ni = 0; ni < 4; ++ni) {
      int row = ni * 16 + lr;
      int xr = (row & 7) << 4;
      bf16x8 b0 = *reinterpret_cast<const bf16x8*>(kbase + (row * 128 + ((lg * 16) ^ xr)));
      bf16x8 b1 = *reinterpret_cast<const bf16x8*>(kbase + (row * 128 + ((64 + lg * 16) ^ xr)));
      s4[ni] = (f32x4){0.f, 0.f, 0.f, 0.f};
      s4[ni] = __builtin_amdgcn_mfma_f32_16x16x32_bf16(b0, aq[0], s4[ni], 0, 0, 0);
      s4[ni] = __builtin_amdgcn_mfma_f32_16x16x32_bf16(b1, aq[1], s4[ni], 0, 0, 0);
    }
    __builtin_amdgcn_s_setprio(0);

    if (kt == qtile) {   // causal mask, diagonal tile only
      #pragma unroll
      for (int ni = 0; ni < 4; ++ni)
        #pragma unroll
        for (int r = 0; r < 4; ++r)
          if (ni * 16 + lg * 4 + r > wid * 16 + lr) s4[ni][r] = -INFINITY;
    }

    // row max: in-lane tree over 16, then fold lanes +-16, +-32
    float rmax;
    {
      float a0 = fmaxf(fmaxf(s4[0][0], s4[0][1]), fmaxf(s4[0][2], s4[0][3]));
      float a1 = fmaxf(fmaxf(s4[1][0], s4[1][1]), fmaxf(s4[1][2], s4[1][3]));
      float a2 = fmaxf(fmaxf(s4[2][0], s4[2][1]), fmaxf(s4[2][2], s4[2][3]));
      float a3 = fmaxf(fmaxf(s4[3][0], s4[3][1]), fmaxf(s4[3][2], s4[3][3]));
      rmax = fmaxf(fmaxf(a0, a1), fmaxf(a2, a3));
      rmax = fmaxf(rmax, __shfl_xor(rmax, 16));
      rmax = fmaxf(rmax, __shfl_xor(rmax, 32));
    }

    // defer-max: rescale only when max grew by > 8 (P bounded by 2^8)
    if (__any(rmax > m_ + 8.f)) {
      float mn = fmaxf(m_, rmax);
      float f = exp2f(m_ - mn);
      m_ = mn;
      ls *= f;
      #pragma unroll
      for (int r = 0; r < 4; ++r) {
        float fo = __shfl(f, lg * 4 + r);   // f for q-row qw+lg*4+r
        #pragma unroll
        for (int ni = 0; ni < 4; ++ni) oacc[ni][r] *= fo;
      }
    }

    // P = exp2(S - m), in-lane sum, pack to bf16, stage to LDS
    float p[4][4];
    float psum = 0.f;
    #pragma unroll
    for (int ni = 0; ni < 4; ++ni) {
      float t0 = exp2f(s4[ni][0] - m_);
      float t1 = exp2f(s4[ni][1] - m_);
      float t2 = exp2f(s4[ni][2] - m_);
      float t3 = exp2f(s4[ni][3] - m_);
      p[ni][0] = t0; p[ni][1] = t1; p[ni][2] = t2; p[ni][3] = t3;
      psum += (t0 + t1) + (t2 + t3);
    }
    psum += __shfl_xor(psum, 16);
    psum += __shfl_xor(psum, 32);
    ls += psum;

    char* pbase = (char*)&p_lds[wid][0];
    const int xq = (lr & 7) << 4;
    #pragma unroll
    for (int ni = 0; ni < 4; ++ni) {
      uint2 w;
      w.x = cvt_pk_bf16(p[ni][0], p[ni][1]);
      w.y = cvt_pk_bf16(p[ni][2], p[ni][3]);
      *reinterpret_cast<uint2*>(pbase + ((lr * 128 + ni * 32 + lg * 8) ^ xq)) = w;
    }

    // P fragments: A-operand rows q=lr, kv contiguous (wave-private LDS)
    bf16x8 pa0 = *reinterpret_cast<const bf16x8*>(pbase + ((lr * 128 + lg * 16) ^ xq));
    bf16x8 pa1 = *reinterpret_cast<const bf16x8*>(pbase + ((lr * 128 + 64 + lg * 16) ^ xq));

    // ctx += P V : B rows are d (V^T tile), K-contig in kv
    const char* vbase = (const char*)&vt_lds[cur][0];
    __builtin_amdgcn_s_setprio(1);
    #pragma unroll
    for (int ni = 0; ni < 4; ++ni) {
      int row = ni * 16 + lr;
      int xr = (row & 7) << 4;
      bf16x8 v0 = *reinterpret_cast<const bf16x8*>(vbase + (row * 128 + ((lg * 16) ^ xr)));
      bf16x8 v1 = *reinterpret_cast<const bf16x8*>(vbase + (row * 128 + ((64 + lg * 16) ^ xr)));
      oacc[ni] = __builtin_amdgcn_mfma_f32_16x16x32_bf16(pa0, v0, oacc[ni], 0, 0, 0);
      oacc[ni] = __builtin_amdgcn_mfma_f32_16x16x32_bf16(pa1, v1, oacc[ni], 0, 0, 0);
    }
    __builtin_amdgcn_s_setprio(0);

    __syncthreads();   // drains vmcnt: next tile staged; this buffer free
    cur ^= 1;
  }

  // write ctx [b][l][h*64+d] bf16 (ls for q-row qw+lg*4+r via shfl)
  #pragma unroll
  for (int r = 0; r < 4; ++r) {
    float inv = 1.0f / __shfl(ls, lg * 4 + r);
    int qr = qw + lg * 4 + r;
    #pragma unroll
    for (int ni = 0; ni < 4; ++ni) {
      int d = ni * 16 + lr;
      ctxb[((size_t)b * SEQ + qr) * 1024 + h * HD + d] = f2bf(oacc[ni][r] * inv);
    }
  }
}

extern "C" void kernel_launch(void* const* d_in, const int* in_sizes, int n_in,
                              void* d_out, int out_size, void* d_ws, size_t ws_size,
                              hipStream_t stream) {
  const float* x   = (const float*)d_in[0];
  const float* w_k = (const float*)d_in[1];
  const float* w_q = (const float*)d_in[2];
  const float* w_v = (const float*)d_in[3];
  const float* w_o = (const float*)d_in[4];
  const float* b_o = (const float*)d_in[5];
  float* out = (float*)d_out;

  char* ws = (char*)d_ws;
  unsigned short* xb   = (unsigned short*)(ws + 0);          //  8 MB [4096][1024]
  unsigned short* wqkv = (unsigned short*)(ws + 8388608);    //  6 MB [3072][1024]  (w_k;w_q;w_v)
  unsigned short* wob  = (unsigned short*)(ws + 14680064);   //  2 MB [1024][1024]
  unsigned short* qb   = (unsigned short*)(ws + 16777216);   //  8 MB [b][h][l][d]
  unsigned short* kb   = (unsigned short*)(ws + 25165824);   //  8 MB [b][h][l][d]
  unsigned short* vtb  = (unsigned short*)(ws + 33554432);   //  8 MB [b][h][d][l]
  unsigned short* ctxb = xb;                                  // reuse x region

  int n = M_TOT * 1024;
  cvt_kernel<<<n / 1024, 256, 0, stream>>>(x, xb, n);
  cvt4_kernel<<<dim3(1024, 4), 256, 0, stream>>>(
      w_k, w_q, w_v, w_o, wqkv, wqkv + 1048576, wqkv + 2097152, wob);

  // QKV: A = xb [4096][1024], B = wqkv [3072][1024]; 128x96 tiles, 1024 blocks
  gemm_tile<96, 0><<<dim3(32, 32), 256, 0, stream>>>(
      xb, wqkv, 1024, qb, kb, vtb, nullptr, nullptr);

  attn_kernel<<<dim3(1024), 256, 0, stream>>>(qb, kb, vtb, ctxb);

  // out = ctx @ w_o^T + b_o ; 128x64 tiles, 512 blocks
  gemm_tile<64, 1><<<dim3(32, 16), 256, 0, stream>>>(
      ctxb, wob, 1024, nullptr, nullptr, nullptr, b_o, out);
}